// Round 1
// baseline (264.562 us; speedup 1.0000x reference)
//
#include <hip/hip_runtime.h>

#define NN 50000
#define EE 800000
#define DD 128
#define BN_EPS 1e-5f
#define XCONV_B 3125    // N*D/8/256
#define BIN_BLOCKS 200
#define BIN_EDGES 4000  // per block; 200*4000 == EE
#define NBUCK 1563      // ceil(50000/32): 32-row buckets
#define BCAP 1024       // bucket capacity (mean 512, ~22 sigma headroom)
#define NREP 32         // BN-stat replica count
#define GEMM_B 782      // ceil(NN/64) for gemm2
#define LDA 136         // padded LDS A-tile stride (bf16): 272B -> 2-way banks

typedef __attribute__((ext_vector_type(8))) short bf16x8;
typedef __attribute__((ext_vector_type(4))) float f32x4;
typedef __attribute__((ext_vector_type(8))) unsigned short u16x8;

__device__ inline unsigned short f2bf(float f) {  // RNE fp32 -> bf16
  unsigned int u = __float_as_uint(f);
  u = (u + 0x7fffu + ((u >> 16) & 1u)) >> 16;
  return (unsigned short)u;
}
__device__ inline float bf2f(unsigned short b) {
  return __uint_as_float(((unsigned int)b) << 16);
}

// ---------------------------------------------------------------------------
// Memory plan (byte offsets into d_out, 25.6MB; scratch dead before k_bnrelu
// overwrites d_out with the fp32 result):
//   [0, +6256B)     bcur[NBUCK] bucket cursors + done[1] (gemm2 last-block)
//   [4.0M, 16.8M)   xb  = bf16(x)                  (dies after k_aggemm1)
//   [16.8M, 23.2M)  bbuf = u32[NBUCK*BCAP] packed (row&31)<<16|col
//   [23.28M,+32KB)  W1b; [23.36M,+32KB) W2b
//   [23.5M, +64KB)  reps: sum1[NREP][128] | sumsq1 | sum2 | sumsq2
// d_ws (25.6MB + 4KB): h1b | h2b | stats tail: scale2[128] | shift2[128]
// 5 dispatches. Lessons pinned: grid.sync ~100us/sync (R8); launch gap
// ~13us/dispatch (R7-R9); 2-wave/1563-block aggemm was grid-limited at
// 27.6% occupancy -> 4-wave blocks here (24.4 waves/CU potential);
// k_bnstats2 folded into k_gemm2 via threadfence+done-counter (saves a gap).
// ---------------------------------------------------------------------------

// K0: fused prep — x->bf16, W1->bf16, W2->bf16, zero bcur+done + stat replicas
__global__ __launch_bounds__(256) void k_prep(const float* __restrict__ x,
                                              const float* __restrict__ W1,
                                              const float* __restrict__ W2,
                                              unsigned short* __restrict__ xb,
                                              unsigned short* __restrict__ W1b,
                                              unsigned short* __restrict__ W2b,
                                              int* __restrict__ bcur,
                                              float* __restrict__ reps) {
  const int b = blockIdx.x;
  const int t = threadIdx.x;
  if (b < XCONV_B) {
    const int gid = b * 256 + t;
    const float4 v0 = ((const float4*)x)[gid * 2];
    const float4 v1 = ((const float4*)x)[gid * 2 + 1];
    ushort4 o0, o1;
    o0.x = f2bf(v0.x); o0.y = f2bf(v0.y); o0.z = f2bf(v0.z); o0.w = f2bf(v0.w);
    o1.x = f2bf(v1.x); o1.y = f2bf(v1.y); o1.z = f2bf(v1.z); o1.w = f2bf(v1.w);
    ((ushort4*)xb)[gid * 2] = o0;
    ((ushort4*)xb)[gid * 2 + 1] = o1;
    if (gid <= NBUCK) bcur[gid] = 0;  // includes done counter at [NBUCK]
    if (gid < 4 * NREP * DD) reps[gid] = 0.0f;  // 16384 floats
  } else if (b < XCONV_B + 16) {
    const int gid = (b - XCONV_B) * 256 + t;
    const float4 v = ((const float4*)W1)[gid];
    ushort4 o;
    o.x = f2bf(v.x); o.y = f2bf(v.y); o.z = f2bf(v.z); o.w = f2bf(v.w);
    ((ushort4*)W1b)[gid] = o;
  } else {
    const int gid = (b - XCONV_B - 16) * 256 + t;
    const float4 v = ((const float4*)W2)[gid];
    ushort4 o;
    o.x = f2bf(v.x); o.y = f2bf(v.y); o.z = f2bf(v.z); o.w = f2bf(v.w);
    ((ushort4*)W2b)[gid] = o;
  }
}

// K1: bin edges into fixed-capacity 32-row buckets (block-private segments
// via one global reservation per bucket — HBM write amp stays 1x).
__global__ __launch_bounds__(256) void k_bin0(const int* __restrict__ rows,
                                              const int* __restrict__ cols,
                                              int* __restrict__ bcur,
                                              unsigned int* __restrict__ bbuf) {
  __shared__ int hist[NBUCK];
  __shared__ int lbase[NBUCK];
  const int t = threadIdx.x;
  for (int i = t; i < NBUCK; i += 256) hist[i] = 0;
  __syncthreads();
  const int e0 = blockIdx.x * BIN_EDGES;
  int er[16], ec[16];
#pragma unroll
  for (int i = 0; i < 16; ++i) {
    const int idx = t + i * 256;
    if (idx < BIN_EDGES) {
      er[i] = rows[e0 + idx];
      ec[i] = cols[e0 + idx];
      atomicAdd(&hist[er[i] >> 5], 1);
    }
  }
  __syncthreads();
  for (int i = t; i < NBUCK; i += 256) {
    const int c = hist[i];
    lbase[i] = (c > 0) ? atomicAdd(&bcur[i], c) : 0;
    hist[i] = 0;  // reuse as local placement cursor
  }
  __syncthreads();
#pragma unroll
  for (int i = 0; i < 16; ++i) {
    const int idx = t + i * 256;
    if (idx < BIN_EDGES) {
      const int bk = er[i] >> 5;
      const int lp = lbase[bk] + atomicAdd(&hist[bk], 1);
      if (lp < BCAP)  // statistically impossible overflow; memory-safety clamp
        bbuf[(size_t)bk * BCAP + lp] =
            ((unsigned)(er[i] & 31) << 16) | (unsigned)ec[i];
    }
  }
}

// K2: FUSED per-bucket aggregation + GEMM1. Block = bucket b = rows
// [32b,32b+32), 256 threads (4 waves — doubles latency-hiding vs 2-wave
// version that measured 27.6% occupancy / 55us). Phase A: LDS counting sort
// (wave-0 shfl scan) + wave-per-row gather with 4-deep load pipelining;
// aggregated bf16 rows land in a padded LDS tile. Phase B: MFMA GEMM, waves
// tile 2x2 over the 32x128 output (A from LDS, B=W1b from global); epilogue
// writes h1b + BN1 replica stats.
__global__ __launch_bounds__(256) void k_aggemm1(
    const unsigned short* __restrict__ xb, const float* __restrict__ eps,
    const int* __restrict__ bcnt, const unsigned int* __restrict__ bbuf,
    const unsigned short* __restrict__ W, const float* __restrict__ bias,
    unsigned short* __restrict__ outb, float* __restrict__ sum1r,
    float* __restrict__ sumsq1r) {
  __shared__ unsigned short scols[BCAP];   // 2KB sorted col ids
  __shared__ unsigned short sA[32 * LDA];  // 8.7KB padded A tile (bf16)
  __shared__ int rcnt[32];
  __shared__ int roff[33];
  __shared__ float bsum[DD];
  __shared__ float bsq[DD];
  const int t = threadIdx.x;
  const int bk = blockIdx.x;
  const int wv = t >> 6;       // 0..3
  const int lane = t & 63;
  const int sub = lane >> 4;   // 0..3 (== quad in phase B)
  const int l16 = lane & 15;

  int n = bcnt[bk];
  n = n < BCAP ? n : BCAP;
  if (t < 32) rcnt[t] = 0;
  if (t < DD) { bsum[t] = 0.f; bsq[t] = 0.f; }
  __syncthreads();

  // ---- phase A1: load bucket entries + per-row count
  unsigned int ent[4];
  int nl = 0;
  for (int i = t; i < n; i += 256) {
    const unsigned int e = bbuf[(size_t)bk * BCAP + i];
    ent[nl++] = e;
    atomicAdd(&rcnt[e >> 16], 1);
  }
  __syncthreads();
  // exclusive scan of 32 row-counts — wave 0 only, shfl-based (no barriers)
  if (t < 64) {
    int v = (t < 32) ? rcnt[t] : 0;
#pragma unroll
    for (int off = 1; off < 32; off <<= 1) {
      const int u = __shfl_up(v, off);
      if (lane >= off) v += u;
    }
    if (t < 32) roff[t] = v - rcnt[t];
    if (t == 31) roff[32] = v;
    if (t < 32) rcnt[t] = 0;  // reuse as placement cursor (wave-sync safe)
  }
  __syncthreads();
  // place col ids row-sorted
  for (int i = 0; i < nl; ++i) {
    const int r = ent[i] >> 16;
    const int pos = roff[r] + atomicAdd(&rcnt[r], 1);
    scols[pos] = (unsigned short)(ent[i] & 0xffffu);
  }
  __syncthreads();

  // ---- phase A2: gather-aggregate; wave wv owns rows wv, wv+4, ...
  {
    const float s = 1.0f + eps[0];
    for (int r = wv; r < 32; r += 4) {
      const int v = bk * 32 + r;
      float acc[8];
#pragma unroll
      for (int j = 0; j < 8; ++j) acc[j] = 0.f;
      if (v < NN) {
        if (sub == 0) {
          const u16x8 a = *(const u16x8*)(xb + (size_t)v * DD + l16 * 8);
#pragma unroll
          for (int j = 0; j < 8; ++j) acc[j] = s * bf2f(a[j]);
        }
        const int beg = roff[r];
        const int end = roff[r + 1];
        int i = beg + sub;
        // 4-deep load pipeline per sub (16 rows in flight per wave)
        for (; i + 12 < end; i += 16) {
          const int u0 = scols[i];
          const int u1 = scols[i + 4];
          const int u2 = scols[i + 8];
          const int u3 = scols[i + 12];
          const u16x8 a = *(const u16x8*)(xb + (size_t)u0 * DD + l16 * 8);
          const u16x8 b = *(const u16x8*)(xb + (size_t)u1 * DD + l16 * 8);
          const u16x8 c = *(const u16x8*)(xb + (size_t)u2 * DD + l16 * 8);
          const u16x8 d = *(const u16x8*)(xb + (size_t)u3 * DD + l16 * 8);
#pragma unroll
          for (int j = 0; j < 8; ++j)
            acc[j] += (bf2f(a[j]) + bf2f(b[j])) + (bf2f(c[j]) + bf2f(d[j]));
        }
        for (; i + 4 < end; i += 8) {
          const int u0 = scols[i];
          const int u1 = scols[i + 4];
          const u16x8 a = *(const u16x8*)(xb + (size_t)u0 * DD + l16 * 8);
          const u16x8 b = *(const u16x8*)(xb + (size_t)u1 * DD + l16 * 8);
#pragma unroll
          for (int j = 0; j < 8; ++j) acc[j] += bf2f(a[j]) + bf2f(b[j]);
        }
        if (i < end) {
          const int u = scols[i];
          const u16x8 a = *(const u16x8*)(xb + (size_t)u * DD + l16 * 8);
#pragma unroll
          for (int j = 0; j < 8; ++j) acc[j] += bf2f(a[j]);
        }
      }
#pragma unroll
      for (int j = 0; j < 8; ++j) {
        acc[j] += __shfl_xor(acc[j], 16);
        acc[j] += __shfl_xor(acc[j], 32);
      }
      if (sub == 0) {
        u16x8 o;
#pragma unroll
        for (int j = 0; j < 8; ++j) o[j] = f2bf(acc[j]);
        *(u16x8*)(&sA[r * LDA + l16 * 8]) = o;  // 2-way bank alias: free
      }
    }
  }
  __syncthreads();

  // ---- phase B: MFMA GEMM; waves tile 2(rows) x 2(cols) over 32x128
  const int wr = wv & 1;   // row half
  const int wc = wv >> 1;  // col half
  f32x4 acc[4];
#pragma unroll
  for (int nn = 0; nn < 4; ++nn) acc[nn] = (f32x4){0.f, 0.f, 0.f, 0.f};
#pragma unroll
  for (int kk = 0; kk < 4; ++kk) {
    const bf16x8 af =
        *(const bf16x8*)(&sA[(wr * 16 + l16) * LDA + kk * 32 + sub * 8]);
#pragma unroll
    for (int nn = 0; nn < 4; ++nn) {
      const bf16x8 bf = *(const bf16x8*)(
          W + (size_t)(wc * 64 + nn * 16 + l16) * DD + sub * 8 + kk * 32);
      acc[nn] = __builtin_amdgcn_mfma_f32_16x16x32_bf16(af, bf, acc[nn], 0, 0, 0);
    }
  }
  const int orow0 = bk * 32 + wr * 16 + sub * 4;
#pragma unroll
  for (int nn = 0; nn < 4; ++nn) {
    const int col = wc * 64 + nn * 16 + l16;
    const float bv = bias[col];
    float sv = 0.f, qv = 0.f;
#pragma unroll
    for (int r = 0; r < 4; ++r) {
      const int row = orow0 + r;
      if (row < NN) {
        const float o = acc[nn][r] + bv;
        outb[(size_t)row * DD + col] = f2bf(o);
        sv += o; qv += o * o;
      }
    }
    sv += __shfl_xor(sv, 16); qv += __shfl_xor(qv, 16);
    sv += __shfl_xor(sv, 32); qv += __shfl_xor(qv, 32);
    if (sub == 0) { atomicAdd(&bsum[col], sv); atomicAdd(&bsq[col], qv); }
  }
  __syncthreads();
  if (t < DD) {
    const int rep = (bk & (NREP - 1)) * DD;
    atomicAdd(&sum1r[rep + t], bsum[t]);
    atomicAdd(&sumsq1r[rep + t], bsq[t]);
  }
}

// ---------------------------------------------------------------------------
// GEMM2: collapse sum1 replicas -> BN1 scale/shift in-block; A=relu(BN1(h1b))
// on the fly; out = h2b bf16; BN2 stats into replicas. The LAST block to
// finish (done-counter) collapses the BN2 replicas into scale2/shift2 —
// replaces the former k_bnstats2 dispatch (~13us launch gap saved).
// ---------------------------------------------------------------------------
__global__ __launch_bounds__(256) void k_gemm2(const unsigned short* __restrict__ A,
                                               const float* __restrict__ sum1r,
                                               const float* __restrict__ sumsq1r,
                                               const float* __restrict__ gamma,
                                               const float* __restrict__ beta,
                                               const unsigned short* __restrict__ W,
                                               const float* __restrict__ bias,
                                               unsigned short* __restrict__ outb,
                                               float* __restrict__ sum2r,
                                               float* __restrict__ sumsq2r,
                                               const float* __restrict__ gamma2,
                                               const float* __restrict__ beta2,
                                               float* __restrict__ scale2,
                                               float* __restrict__ shift2,
                                               int* __restrict__ done) {
  __shared__ float lsc[DD];
  __shared__ float lsh[DD];
  __shared__ float bsum[DD];
  __shared__ float bsq[DD];
  const int tid = threadIdx.x;
  const int wv = tid >> 6;
  const int lane = tid & 63;
  const int quad = lane >> 4;
  const int l16 = lane & 15;
  if (tid < DD) {
    float sm = 0.f, qm = 0.f;
#pragma unroll
    for (int r = 0; r < NREP; ++r) {
      sm += sum1r[r * DD + tid];
      qm += sumsq1r[r * DD + tid];
    }
    const float inv_n = 1.0f / (float)NN;
    const float mean = sm * inv_n;
    const float var = qm * inv_n - mean * mean;
    const float s = gamma[tid] * rsqrtf(var + BN_EPS);
    lsc[tid] = s;
    lsh[tid] = beta[tid] - mean * s;
    bsum[tid] = 0.f;
    bsq[tid] = 0.f;
  }
  __syncthreads();

  const int rowbase = blockIdx.x * 64 + wv * 16 + l16;
  const int arow = rowbase < NN ? rowbase : NN - 1;
  const unsigned short* aptr = A + (size_t)arow * DD + quad * 8;

  f32x4 acc[8];
#pragma unroll
  for (int n = 0; n < 8; ++n) acc[n] = (f32x4){0.f, 0.f, 0.f, 0.f};
#pragma unroll
  for (int kk = 0; kk < 4; ++kk) {
    const int kbase = kk * 32 + quad * 8;
    const u16x8 a = *(const u16x8*)(aptr + kk * 32);
    const float4 s0 = *(const float4*)&lsc[kbase];
    const float4 s1 = *(const float4*)&lsc[kbase + 4];
    const float4 h0 = *(const float4*)&lsh[kbase];
    const float4 h1 = *(const float4*)&lsh[kbase + 4];
    bf16x8 af;
    af[0] = (short)f2bf(fmaxf(fmaf(s0.x, bf2f(a[0]), h0.x), 0.f));
    af[1] = (short)f2bf(fmaxf(fmaf(s0.y, bf2f(a[1]), h0.y), 0.f));
    af[2] = (short)f2bf(fmaxf(fmaf(s0.z, bf2f(a[2]), h0.z), 0.f));
    af[3] = (short)f2bf(fmaxf(fmaf(s0.w, bf2f(a[3]), h0.w), 0.f));
    af[4] = (short)f2bf(fmaxf(fmaf(s1.x, bf2f(a[4]), h1.x), 0.f));
    af[5] = (short)f2bf(fmaxf(fmaf(s1.y, bf2f(a[5]), h1.y), 0.f));
    af[6] = (short)f2bf(fmaxf(fmaf(s1.z, bf2f(a[6]), h1.z), 0.f));
    af[7] = (short)f2bf(fmaxf(fmaf(s1.w, bf2f(a[7]), h1.w), 0.f));
#pragma unroll
    for (int n = 0; n < 8; ++n) {
      const bf16x8 bf =
          *(const bf16x8*)(W + (size_t)(n * 16 + l16) * DD + kbase);
      acc[n] = __builtin_amdgcn_mfma_f32_16x16x32_bf16(af, bf, acc[n], 0, 0, 0);
    }
  }
  const int orow0 = blockIdx.x * 64 + wv * 16 + quad * 4;
#pragma unroll
  for (int n = 0; n < 8; ++n) {
    const int col = n * 16 + l16;
    const float bv = bias[col];
    float sv = 0.f, qv = 0.f;
#pragma unroll
    for (int r = 0; r < 4; ++r) {
      const int row = orow0 + r;
      if (row < NN) {
        const float o = acc[n][r] + bv;
        outb[(size_t)row * DD + col] = f2bf(o);
        sv += o; qv += o * o;
      }
    }
    sv += __shfl_xor(sv, 16); qv += __shfl_xor(qv, 16);
    sv += __shfl_xor(sv, 32); qv += __shfl_xor(qv, 32);
    if (quad == 0) { atomicAdd(&bsum[col], sv); atomicAdd(&bsq[col], qv); }
  }
  __syncthreads();
  if (tid < DD) {
    const int rep = (blockIdx.x & (NREP - 1)) * DD;
    atomicAdd(&sum2r[rep + tid], bsum[tid]);
    atomicAdd(&sumsq2r[rep + tid], bsq[tid]);
  }

  // ---- last-block BN2 replica collapse (replaces k_bnstats2)
  __threadfence();  // order our replica RMWs before the done RMW
  __shared__ int amlast;
  if (tid == 0) amlast = (atomicAdd(done, 1) == GEMM_B - 1) ? 1 : 0;
  __syncthreads();
  if (amlast) {
    __threadfence();  // acquire: invalidate stale cached replica lines
    if (tid < DD) {
      float sm = 0.f, qm = 0.f;
#pragma unroll
      for (int r = 0; r < NREP; ++r) {
        sm += __hip_atomic_load(&sum2r[r * DD + tid], __ATOMIC_RELAXED,
                                __HIP_MEMORY_SCOPE_AGENT);
        qm += __hip_atomic_load(&sumsq2r[r * DD + tid], __ATOMIC_RELAXED,
                                __HIP_MEMORY_SCOPE_AGENT);
      }
      const float inv_n = 1.0f / (float)NN;
      const float mean = sm * inv_n;
      const float var = qm * inv_n - mean * mean;
      const float sc = gamma2[tid] * rsqrtf(var + BN_EPS);
      scale2[tid] = sc;
      shift2[tid] = beta2[tid] - mean * sc;
    }
  }
}

// K4: final BN2 + ReLU -> fp32 out
__global__ __launch_bounds__(256) void k_bnrelu(const unsigned short* __restrict__ in,
                                                const float* __restrict__ scale,
                                                const float* __restrict__ shift,
                                                float* __restrict__ out) {
  __shared__ float lsc[DD];
  __shared__ float lsh[DD];
  const int t = threadIdx.x;
  if (t < DD) {
    lsc[t] = scale[t];
    lsh[t] = shift[t];
  }
  __syncthreads();
  const int gid = blockIdx.x * 256 + t;
  const int c = (gid & 15) * 8;
  const u16x8 a = ((const u16x8*)in)[gid];
  const float4 sc0 = *(const float4*)&lsc[c];
  const float4 sc1 = *(const float4*)&lsc[c + 4];
  const float4 sh0 = *(const float4*)&lsh[c];
  const float4 sh1 = *(const float4*)&lsh[c + 4];
  float4 o0, o1;
  o0.x = fmaxf(fmaf(sc0.x, bf2f(a[0]), sh0.x), 0.f);
  o0.y = fmaxf(fmaf(sc0.y, bf2f(a[1]), sh0.y), 0.f);
  o0.z = fmaxf(fmaf(sc0.z, bf2f(a[2]), sh0.z), 0.f);
  o0.w = fmaxf(fmaf(sc0.w, bf2f(a[3]), sh0.w), 0.f);
  o1.x = fmaxf(fmaf(sc1.x, bf2f(a[4]), sh1.x), 0.f);
  o1.y = fmaxf(fmaf(sc1.y, bf2f(a[5]), sh1.y), 0.f);
  o1.z = fmaxf(fmaf(sc1.z, bf2f(a[6]), sh1.z), 0.f);
  o1.w = fmaxf(fmaf(sc1.w, bf2f(a[7]), sh1.w), 0.f);
  ((float4*)out)[gid * 2] = o0;
  ((float4*)out)[gid * 2 + 1] = o1;
}

// ---------------------------------------------------------------------------
extern "C" void kernel_launch(void* const* d_in, const int* in_sizes, int n_in,
                              void* d_out, int out_size, void* d_ws, size_t ws_size,
                              hipStream_t stream) {
  const float* x = (const float*)d_in[0];
  const int* ei = (const int*)d_in[1];
  const float* eps = (const float*)d_in[2];
  const float* W1 = (const float*)d_in[3];
  const float* b1 = (const float*)d_in[4];
  const float* g1 = (const float*)d_in[5];
  const float* be1 = (const float*)d_in[6];
  const float* W2 = (const float*)d_in[7];
  const float* b2 = (const float*)d_in[8];
  const float* g2 = (const float*)d_in[9];
  const float* be2 = (const float*)d_in[10];
  float* out = (float*)d_out;

  const int* rows = ei;
  const int* cols = ei + EE;

  // d_out scratch (dead before k_bnrelu writes d_out)
  int* bcur = (int*)d_out;                                  // NBUCK ints + done
  unsigned short* xb = (unsigned short*)d_out + 2000000;    // byte 4.0M
  unsigned int* bbuf = (unsigned int*)((char*)d_out + 16800000);  // 6.4MB
  unsigned short* W1b = (unsigned short*)d_out + 11640000;  // byte 23.28M
  unsigned short* W2b = (unsigned short*)d_out + 11680000;  // byte 23.36M
  float* reps = (float*)d_out + 5875000;                    // byte 23.5M, 64KB
  float* sum1r = reps;
  float* sumsq1r = reps + NREP * DD;
  float* sum2r = reps + 2 * NREP * DD;
  float* sumsq2r = reps + 3 * NREP * DD;
  int* done = bcur + NBUCK;

  unsigned short* h1b = (unsigned short*)d_ws;        // aggemm1 out
  unsigned short* h2b = h1b + (size_t)NN * DD;        // gemm2 out
  float* stats = (float*)(h1b + (size_t)2 * NN * DD); // 4KB tail of d_ws
  float* scale2 = stats + 0;
  float* shift2 = stats + 128;

  // 1. prep: x/W1/W2 -> bf16, zero bcur+done + stat replicas
  k_prep<<<XCONV_B + 32, 256, 0, stream>>>(x, W1, W2, xb, W1b, W2b, bcur, reps);
  // 2. bin edges into fixed 32-row buckets (packed u32)
  k_bin0<<<BIN_BLOCKS, 256, 0, stream>>>(rows, cols, bcur, bbuf);
  // 3. FUSED per-bucket sort + gather aggregation + GEMM1 -> h1b, BN1 stats
  k_aggemm1<<<NBUCK, 256, 0, stream>>>(xb, eps, bcur, bbuf, W1b, b1, h1b,
                                       sum1r, sumsq1r);
  // 4. GEMM2 (BN1+ReLU on the fly) -> h2b, BN2 stats; last block collapses
  //    BN2 replicas -> scale2/shift2
  k_gemm2<<<GEMM_B, 256, 0, stream>>>(h1b, sum1r, sumsq1r, g1, be1, W2b, b2,
                                      h2b, sum2r, sumsq2r, g2, be2,
                                      scale2, shift2, done);
  // 5. final BN2+ReLU -> fp32 out
  k_bnrelu<<<(NN * DD / 8) / 256, 256, 0, stream>>>(h2b, scale2, shift2, out);
}

// Round 2
// 213.011 us; speedup vs baseline: 1.2420x; 1.2420x over previous
//
#include <hip/hip_runtime.h>

#define NN 50000
#define EE 800000
#define DD 128
#define BN_EPS 1e-5f
#define XCONV_B 3125    // N*D/8/256
#define BIN_BLOCKS 200
#define BIN_EDGES 4000  // per block; 200*4000 == EE
#define NBUCK 1563      // ceil(50000/32): 32-row buckets
#define BCAP 1024       // bucket capacity (mean 512, ~22 sigma headroom)
#define NREP 32         // BN-stat replica count
#define GEMM_B 782      // ceil(NN/64) for gemm2
#define LDA 136         // padded LDS A-tile stride (bf16): 272B -> 2-way banks

typedef __attribute__((ext_vector_type(8))) short bf16x8;
typedef __attribute__((ext_vector_type(4))) float f32x4;
typedef __attribute__((ext_vector_type(8))) unsigned short u16x8;

__device__ inline unsigned short f2bf(float f) {  // RNE fp32 -> bf16
  unsigned int u = __float_as_uint(f);
  u = (u + 0x7fffu + ((u >> 16) & 1u)) >> 16;
  return (unsigned short)u;
}
__device__ inline float bf2f(unsigned short b) {
  return __uint_as_float(((unsigned int)b) << 16);
}

// ---------------------------------------------------------------------------
// Memory plan (byte offsets into d_out, 25.6MB; scratch dead before k_bnrelu
// overwrites d_out with the fp32 result):
//   [0, +6256B)     bcur[NBUCK] bucket cursors + done[1] (gemm2 last-block)
//   [4.0M, 16.8M)   xb  = bf16(x)                  (dies after k_aggemm1)
//   [16.8M, 23.2M)  bbuf = u32[NBUCK*BCAP] packed (row&31)<<16|col
//   [23.28M,+32KB)  W1b; [23.36M,+32KB) W2b
//   [23.5M, +64KB)  reps: sum1[NREP][128] | sumsq1 | sum2 | sumsq2
// d_ws (25.6MB + 4KB): h1b | h2b | stats tail: scale2[128] | shift2[128]
// 5 dispatches. Lessons pinned: grid.sync ~100us/sync (R8); launch gap
// ~13us/dispatch (R7-R9); 2-wave/1563-block aggemm was grid-limited at
// 27.6% occupancy -> 4-wave blocks (R11); __threadfence() in the done-counter
// protocol = per-wave L2 wb/inv flush storm, k_gemm2 89us @ 3% VALUBusy
// (R12) -> fence-free protocol: device-scope atomic RMWs + the vmcnt(0)
// drain that __syncthreads() already performs give the needed ordering.
// ---------------------------------------------------------------------------

// K0: fused prep — x->bf16, W1->bf16, W2->bf16, zero bcur+done + stat replicas
__global__ __launch_bounds__(256) void k_prep(const float* __restrict__ x,
                                              const float* __restrict__ W1,
                                              const float* __restrict__ W2,
                                              unsigned short* __restrict__ xb,
                                              unsigned short* __restrict__ W1b,
                                              unsigned short* __restrict__ W2b,
                                              int* __restrict__ bcur,
                                              float* __restrict__ reps) {
  const int b = blockIdx.x;
  const int t = threadIdx.x;
  if (b < XCONV_B) {
    const int gid = b * 256 + t;
    const float4 v0 = ((const float4*)x)[gid * 2];
    const float4 v1 = ((const float4*)x)[gid * 2 + 1];
    ushort4 o0, o1;
    o0.x = f2bf(v0.x); o0.y = f2bf(v0.y); o0.z = f2bf(v0.z); o0.w = f2bf(v0.w);
    o1.x = f2bf(v1.x); o1.y = f2bf(v1.y); o1.z = f2bf(v1.z); o1.w = f2bf(v1.w);
    ((ushort4*)xb)[gid * 2] = o0;
    ((ushort4*)xb)[gid * 2 + 1] = o1;
    if (gid <= NBUCK) bcur[gid] = 0;  // includes done counter at [NBUCK]
    if (gid < 4 * NREP * DD) reps[gid] = 0.0f;  // 16384 floats
  } else if (b < XCONV_B + 16) {
    const int gid = (b - XCONV_B) * 256 + t;
    const float4 v = ((const float4*)W1)[gid];
    ushort4 o;
    o.x = f2bf(v.x); o.y = f2bf(v.y); o.z = f2bf(v.z); o.w = f2bf(v.w);
    ((ushort4*)W1b)[gid] = o;
  } else {
    const int gid = (b - XCONV_B - 16) * 256 + t;
    const float4 v = ((const float4*)W2)[gid];
    ushort4 o;
    o.x = f2bf(v.x); o.y = f2bf(v.y); o.z = f2bf(v.z); o.w = f2bf(v.w);
    ((ushort4*)W2b)[gid] = o;
  }
}

// K1: bin edges into fixed-capacity 32-row buckets (block-private segments
// via one global reservation per bucket — HBM write amp stays 1x).
__global__ __launch_bounds__(256) void k_bin0(const int* __restrict__ rows,
                                              const int* __restrict__ cols,
                                              int* __restrict__ bcur,
                                              unsigned int* __restrict__ bbuf) {
  __shared__ int hist[NBUCK];
  __shared__ int lbase[NBUCK];
  const int t = threadIdx.x;
  for (int i = t; i < NBUCK; i += 256) hist[i] = 0;
  __syncthreads();
  const int e0 = blockIdx.x * BIN_EDGES;
  int er[16], ec[16];
#pragma unroll
  for (int i = 0; i < 16; ++i) {
    const int idx = t + i * 256;
    if (idx < BIN_EDGES) {
      er[i] = rows[e0 + idx];
      ec[i] = cols[e0 + idx];
      atomicAdd(&hist[er[i] >> 5], 1);
    }
  }
  __syncthreads();
  for (int i = t; i < NBUCK; i += 256) {
    const int c = hist[i];
    lbase[i] = (c > 0) ? atomicAdd(&bcur[i], c) : 0;
    hist[i] = 0;  // reuse as local placement cursor
  }
  __syncthreads();
#pragma unroll
  for (int i = 0; i < 16; ++i) {
    const int idx = t + i * 256;
    if (idx < BIN_EDGES) {
      const int bk = er[i] >> 5;
      const int lp = lbase[bk] + atomicAdd(&hist[bk], 1);
      if (lp < BCAP)  // statistically impossible overflow; memory-safety clamp
        bbuf[(size_t)bk * BCAP + lp] =
            ((unsigned)(er[i] & 31) << 16) | (unsigned)ec[i];
    }
  }
}

// K2: FUSED per-bucket aggregation + GEMM1. Block = bucket b = rows
// [32b,32b+32), 256 threads (4 waves — doubles latency-hiding vs 2-wave
// version that measured 27.6% occupancy / 55us). Phase A: LDS counting sort
// (wave-0 shfl scan) + wave-per-row gather with 4-deep load pipelining;
// aggregated bf16 rows land in a padded LDS tile. Phase B: MFMA GEMM, waves
// tile 2x2 over the 32x128 output (A from LDS, B=W1b from global); epilogue
// writes h1b + BN1 replica stats.
__global__ __launch_bounds__(256) void k_aggemm1(
    const unsigned short* __restrict__ xb, const float* __restrict__ eps,
    const int* __restrict__ bcnt, const unsigned int* __restrict__ bbuf,
    const unsigned short* __restrict__ W, const float* __restrict__ bias,
    unsigned short* __restrict__ outb, float* __restrict__ sum1r,
    float* __restrict__ sumsq1r) {
  __shared__ unsigned short scols[BCAP];   // 2KB sorted col ids
  __shared__ unsigned short sA[32 * LDA];  // 8.7KB padded A tile (bf16)
  __shared__ int rcnt[32];
  __shared__ int roff[33];
  __shared__ float bsum[DD];
  __shared__ float bsq[DD];
  const int t = threadIdx.x;
  const int bk = blockIdx.x;
  const int wv = t >> 6;       // 0..3
  const int lane = t & 63;
  const int sub = lane >> 4;   // 0..3 (== quad in phase B)
  const int l16 = lane & 15;

  int n = bcnt[bk];
  n = n < BCAP ? n : BCAP;
  if (t < 32) rcnt[t] = 0;
  if (t < DD) { bsum[t] = 0.f; bsq[t] = 0.f; }
  __syncthreads();

  // ---- phase A1: load bucket entries + per-row count
  unsigned int ent[4];
  int nl = 0;
  for (int i = t; i < n; i += 256) {
    const unsigned int e = bbuf[(size_t)bk * BCAP + i];
    ent[nl++] = e;
    atomicAdd(&rcnt[e >> 16], 1);
  }
  __syncthreads();
  // exclusive scan of 32 row-counts — wave 0 only, shfl-based (no barriers)
  if (t < 64) {
    int v = (t < 32) ? rcnt[t] : 0;
#pragma unroll
    for (int off = 1; off < 32; off <<= 1) {
      const int u = __shfl_up(v, off);
      if (lane >= off) v += u;
    }
    if (t < 32) roff[t] = v - rcnt[t];
    if (t == 31) roff[32] = v;
    if (t < 32) rcnt[t] = 0;  // reuse as placement cursor (wave-sync safe)
  }
  __syncthreads();
  // place col ids row-sorted
  for (int i = 0; i < nl; ++i) {
    const int r = ent[i] >> 16;
    const int pos = roff[r] + atomicAdd(&rcnt[r], 1);
    scols[pos] = (unsigned short)(ent[i] & 0xffffu);
  }
  __syncthreads();

  // ---- phase A2: gather-aggregate; wave wv owns rows wv, wv+4, ...
  {
    const float s = 1.0f + eps[0];
    for (int r = wv; r < 32; r += 4) {
      const int v = bk * 32 + r;
      float acc[8];
#pragma unroll
      for (int j = 0; j < 8; ++j) acc[j] = 0.f;
      if (v < NN) {
        if (sub == 0) {
          const u16x8 a = *(const u16x8*)(xb + (size_t)v * DD + l16 * 8);
#pragma unroll
          for (int j = 0; j < 8; ++j) acc[j] = s * bf2f(a[j]);
        }
        const int beg = roff[r];
        const int end = roff[r + 1];
        int i = beg + sub;
        // 4-deep load pipeline per sub (16 rows in flight per wave)
        for (; i + 12 < end; i += 16) {
          const int u0 = scols[i];
          const int u1 = scols[i + 4];
          const int u2 = scols[i + 8];
          const int u3 = scols[i + 12];
          const u16x8 a = *(const u16x8*)(xb + (size_t)u0 * DD + l16 * 8);
          const u16x8 b = *(const u16x8*)(xb + (size_t)u1 * DD + l16 * 8);
          const u16x8 c = *(const u16x8*)(xb + (size_t)u2 * DD + l16 * 8);
          const u16x8 d = *(const u16x8*)(xb + (size_t)u3 * DD + l16 * 8);
#pragma unroll
          for (int j = 0; j < 8; ++j)
            acc[j] += (bf2f(a[j]) + bf2f(b[j])) + (bf2f(c[j]) + bf2f(d[j]));
        }
        for (; i + 4 < end; i += 8) {
          const int u0 = scols[i];
          const int u1 = scols[i + 4];
          const u16x8 a = *(const u16x8*)(xb + (size_t)u0 * DD + l16 * 8);
          const u16x8 b = *(const u16x8*)(xb + (size_t)u1 * DD + l16 * 8);
#pragma unroll
          for (int j = 0; j < 8; ++j) acc[j] += bf2f(a[j]) + bf2f(b[j]);
        }
        if (i < end) {
          const int u = scols[i];
          const u16x8 a = *(const u16x8*)(xb + (size_t)u * DD + l16 * 8);
#pragma unroll
          for (int j = 0; j < 8; ++j) acc[j] += bf2f(a[j]);
        }
      }
#pragma unroll
      for (int j = 0; j < 8; ++j) {
        acc[j] += __shfl_xor(acc[j], 16);
        acc[j] += __shfl_xor(acc[j], 32);
      }
      if (sub == 0) {
        u16x8 o;
#pragma unroll
        for (int j = 0; j < 8; ++j) o[j] = f2bf(acc[j]);
        *(u16x8*)(&sA[r * LDA + l16 * 8]) = o;  // 2-way bank alias: free
      }
    }
  }
  __syncthreads();

  // ---- phase B: MFMA GEMM; waves tile 2(rows) x 2(cols) over 32x128
  const int wr = wv & 1;   // row half
  const int wc = wv >> 1;  // col half
  f32x4 acc[4];
#pragma unroll
  for (int nn = 0; nn < 4; ++nn) acc[nn] = (f32x4){0.f, 0.f, 0.f, 0.f};
#pragma unroll
  for (int kk = 0; kk < 4; ++kk) {
    const bf16x8 af =
        *(const bf16x8*)(&sA[(wr * 16 + l16) * LDA + kk * 32 + sub * 8]);
#pragma unroll
    for (int nn = 0; nn < 4; ++nn) {
      const bf16x8 bf = *(const bf16x8*)(
          W + (size_t)(wc * 64 + nn * 16 + l16) * DD + sub * 8 + kk * 32);
      acc[nn] = __builtin_amdgcn_mfma_f32_16x16x32_bf16(af, bf, acc[nn], 0, 0, 0);
    }
  }
  const int orow0 = bk * 32 + wr * 16 + sub * 4;
#pragma unroll
  for (int nn = 0; nn < 4; ++nn) {
    const int col = wc * 64 + nn * 16 + l16;
    const float bv = bias[col];
    float sv = 0.f, qv = 0.f;
#pragma unroll
    for (int r = 0; r < 4; ++r) {
      const int row = orow0 + r;
      if (row < NN) {
        const float o = acc[nn][r] + bv;
        outb[(size_t)row * DD + col] = f2bf(o);
        sv += o; qv += o * o;
      }
    }
    sv += __shfl_xor(sv, 16); qv += __shfl_xor(qv, 16);
    sv += __shfl_xor(sv, 32); qv += __shfl_xor(qv, 32);
    if (sub == 0) { atomicAdd(&bsum[col], sv); atomicAdd(&bsq[col], qv); }
  }
  __syncthreads();
  if (t < DD) {
    const int rep = (bk & (NREP - 1)) * DD;
    atomicAdd(&sum1r[rep + t], bsum[t]);
    atomicAdd(&sumsq1r[rep + t], bsq[t]);
  }
}

// ---------------------------------------------------------------------------
// GEMM2: collapse sum1 replicas -> BN1 scale/shift in-block; A=relu(BN1(h1b))
// on the fly; out = h2b bf16; BN2 stats into replicas. The LAST block to
// finish (done-counter) collapses the BN2 replicas into scale2/shift2 —
// replaces the former k_bnstats2 dispatch (~13us launch gap saved).
// FENCE-FREE protocol (R12 lesson: __threadfence() = per-wave L2 wb/inv
// flush storm, 89us @ 3% VALUBusy): replica updates are device-scope atomic
// RMWs completing at the coherence point; __syncthreads() drains vmcnt(0)
// before s_barrier, so tid0's done-RMW is HW-ordered after this block's
// replica RMWs; the last block reads replicas with agent-scope atomic loads.
// ---------------------------------------------------------------------------
__global__ __launch_bounds__(256) void k_gemm2(const unsigned short* __restrict__ A,
                                               const float* __restrict__ sum1r,
                                               const float* __restrict__ sumsq1r,
                                               const float* __restrict__ gamma,
                                               const float* __restrict__ beta,
                                               const unsigned short* __restrict__ W,
                                               const float* __restrict__ bias,
                                               unsigned short* __restrict__ outb,
                                               float* __restrict__ sum2r,
                                               float* __restrict__ sumsq2r,
                                               const float* __restrict__ gamma2,
                                               const float* __restrict__ beta2,
                                               float* __restrict__ scale2,
                                               float* __restrict__ shift2,
                                               int* __restrict__ done) {
  __shared__ float lsc[DD];
  __shared__ float lsh[DD];
  __shared__ float bsum[DD];
  __shared__ float bsq[DD];
  __shared__ int amlast;
  const int tid = threadIdx.x;
  const int wv = tid >> 6;
  const int lane = tid & 63;
  const int quad = lane >> 4;
  const int l16 = lane & 15;
  if (tid < DD) {
    float sm = 0.f, qm = 0.f;
#pragma unroll
    for (int r = 0; r < NREP; ++r) {
      sm += sum1r[r * DD + tid];
      qm += sumsq1r[r * DD + tid];
    }
    const float inv_n = 1.0f / (float)NN;
    const float mean = sm * inv_n;
    const float var = qm * inv_n - mean * mean;
    const float s = gamma[tid] * rsqrtf(var + BN_EPS);
    lsc[tid] = s;
    lsh[tid] = beta[tid] - mean * s;
    bsum[tid] = 0.f;
    bsq[tid] = 0.f;
  }
  __syncthreads();

  const int rowbase = blockIdx.x * 64 + wv * 16 + l16;
  const int arow = rowbase < NN ? rowbase : NN - 1;
  const unsigned short* aptr = A + (size_t)arow * DD + quad * 8;

  f32x4 acc[8];
#pragma unroll
  for (int n = 0; n < 8; ++n) acc[n] = (f32x4){0.f, 0.f, 0.f, 0.f};
#pragma unroll
  for (int kk = 0; kk < 4; ++kk) {
    const int kbase = kk * 32 + quad * 8;
    const u16x8 a = *(const u16x8*)(aptr + kk * 32);
    const float4 s0 = *(const float4*)&lsc[kbase];
    const float4 s1 = *(const float4*)&lsc[kbase + 4];
    const float4 h0 = *(const float4*)&lsh[kbase];
    const float4 h1 = *(const float4*)&lsh[kbase + 4];
    bf16x8 af;
    af[0] = (short)f2bf(fmaxf(fmaf(s0.x, bf2f(a[0]), h0.x), 0.f));
    af[1] = (short)f2bf(fmaxf(fmaf(s0.y, bf2f(a[1]), h0.y), 0.f));
    af[2] = (short)f2bf(fmaxf(fmaf(s0.z, bf2f(a[2]), h0.z), 0.f));
    af[3] = (short)f2bf(fmaxf(fmaf(s0.w, bf2f(a[3]), h0.w), 0.f));
    af[4] = (short)f2bf(fmaxf(fmaf(s1.x, bf2f(a[4]), h1.x), 0.f));
    af[5] = (short)f2bf(fmaxf(fmaf(s1.y, bf2f(a[5]), h1.y), 0.f));
    af[6] = (short)f2bf(fmaxf(fmaf(s1.z, bf2f(a[6]), h1.z), 0.f));
    af[7] = (short)f2bf(fmaxf(fmaf(s1.w, bf2f(a[7]), h1.w), 0.f));
#pragma unroll
    for (int n = 0; n < 8; ++n) {
      const bf16x8 bf =
          *(const bf16x8*)(W + (size_t)(n * 16 + l16) * DD + kbase);
      acc[n] = __builtin_amdgcn_mfma_f32_16x16x32_bf16(af, bf, acc[n], 0, 0, 0);
    }
  }
  const int orow0 = blockIdx.x * 64 + wv * 16 + quad * 4;
#pragma unroll
  for (int n = 0; n < 8; ++n) {
    const int col = n * 16 + l16;
    const float bv = bias[col];
    float sv = 0.f, qv = 0.f;
#pragma unroll
    for (int r = 0; r < 4; ++r) {
      const int row = orow0 + r;
      if (row < NN) {
        const float o = acc[n][r] + bv;
        outb[(size_t)row * DD + col] = f2bf(o);
        sv += o; qv += o * o;
      }
    }
    sv += __shfl_xor(sv, 16); qv += __shfl_xor(qv, 16);
    sv += __shfl_xor(sv, 32); qv += __shfl_xor(qv, 32);
    if (quad == 0) { atomicAdd(&bsum[col], sv); atomicAdd(&bsq[col], qv); }
  }
  __syncthreads();
  if (tid < DD) {
    const int rep = (blockIdx.x & (NREP - 1)) * DD;
    atomicAdd(&sum2r[rep + tid], bsum[tid]);
    atomicAdd(&sumsq2r[rep + tid], bsq[tid]);
  }

  // ---- last-block BN2 replica collapse (fence-free; see header comment).
  // __syncthreads() drains each wave's replica RMWs (vmcnt(0)) before tid0
  // can issue the done RMW at the same coherence point.
  __syncthreads();
  if (tid == 0) amlast = (atomicAdd(done, 1) == GEMM_B - 1) ? 1 : 0;
  __syncthreads();
  if (amlast) {
    if (tid < DD) {
      float sm = 0.f, qm = 0.f;
#pragma unroll
      for (int r = 0; r < NREP; ++r) {
        sm += __hip_atomic_load(&sum2r[r * DD + tid], __ATOMIC_RELAXED,
                                __HIP_MEMORY_SCOPE_AGENT);
        qm += __hip_atomic_load(&sumsq2r[r * DD + tid], __ATOMIC_RELAXED,
                                __HIP_MEMORY_SCOPE_AGENT);
      }
      const float inv_n = 1.0f / (float)NN;
      const float mean = sm * inv_n;
      const float var = qm * inv_n - mean * mean;
      const float sc = gamma2[tid] * rsqrtf(var + BN_EPS);
      scale2[tid] = sc;
      shift2[tid] = beta2[tid] - mean * sc;
    }
  }
}

// K4: final BN2 + ReLU -> fp32 out
__global__ __launch_bounds__(256) void k_bnrelu(const unsigned short* __restrict__ in,
                                                const float* __restrict__ scale,
                                                const float* __restrict__ shift,
                                                float* __restrict__ out) {
  __shared__ float lsc[DD];
  __shared__ float lsh[DD];
  const int t = threadIdx.x;
  if (t < DD) {
    lsc[t] = scale[t];
    lsh[t] = shift[t];
  }
  __syncthreads();
  const int gid = blockIdx.x * 256 + t;
  const int c = (gid & 15) * 8;
  const u16x8 a = ((const u16x8*)in)[gid];
  const float4 sc0 = *(const float4*)&lsc[c];
  const float4 sc1 = *(const float4*)&lsc[c + 4];
  const float4 sh0 = *(const float4*)&lsh[c];
  const float4 sh1 = *(const float4*)&lsh[c + 4];
  float4 o0, o1;
  o0.x = fmaxf(fmaf(sc0.x, bf2f(a[0]), sh0.x), 0.f);
  o0.y = fmaxf(fmaf(sc0.y, bf2f(a[1]), sh0.y), 0.f);
  o0.z = fmaxf(fmaf(sc0.z, bf2f(a[2]), sh0.z), 0.f);
  o0.w = fmaxf(fmaf(sc0.w, bf2f(a[3]), sh0.w), 0.f);
  o1.x = fmaxf(fmaf(sc1.x, bf2f(a[4]), sh1.x), 0.f);
  o1.y = fmaxf(fmaf(sc1.y, bf2f(a[5]), sh1.y), 0.f);
  o1.z = fmaxf(fmaf(sc1.z, bf2f(a[6]), sh1.z), 0.f);
  o1.w = fmaxf(fmaf(sc1.w, bf2f(a[7]), sh1.w), 0.f);
  ((float4*)out)[gid * 2] = o0;
  ((float4*)out)[gid * 2 + 1] = o1;
}

// ---------------------------------------------------------------------------
extern "C" void kernel_launch(void* const* d_in, const int* in_sizes, int n_in,
                              void* d_out, int out_size, void* d_ws, size_t ws_size,
                              hipStream_t stream) {
  const float* x = (const float*)d_in[0];
  const int* ei = (const int*)d_in[1];
  const float* eps = (const float*)d_in[2];
  const float* W1 = (const float*)d_in[3];
  const float* b1 = (const float*)d_in[4];
  const float* g1 = (const float*)d_in[5];
  const float* be1 = (const float*)d_in[6];
  const float* W2 = (const float*)d_in[7];
  const float* b2 = (const float*)d_in[8];
  const float* g2 = (const float*)d_in[9];
  const float* be2 = (const float*)d_in[10];
  float* out = (float*)d_out;

  const int* rows = ei;
  const int* cols = ei + EE;

  // d_out scratch (dead before k_bnrelu writes d_out)
  int* bcur = (int*)d_out;                                  // NBUCK ints + done
  unsigned short* xb = (unsigned short*)d_out + 2000000;    // byte 4.0M
  unsigned int* bbuf = (unsigned int*)((char*)d_out + 16800000);  // 6.4MB
  unsigned short* W1b = (unsigned short*)d_out + 11640000;  // byte 23.28M
  unsigned short* W2b = (unsigned short*)d_out + 11680000;  // byte 23.36M
  float* reps = (float*)d_out + 5875000;                    // byte 23.5M, 64KB
  float* sum1r = reps;
  float* sumsq1r = reps + NREP * DD;
  float* sum2r = reps + 2 * NREP * DD;
  float* sumsq2r = reps + 3 * NREP * DD;
  int* done = bcur + NBUCK;

  unsigned short* h1b = (unsigned short*)d_ws;        // aggemm1 out
  unsigned short* h2b = h1b + (size_t)NN * DD;        // gemm2 out
  float* stats = (float*)(h1b + (size_t)2 * NN * DD); // 4KB tail of d_ws
  float* scale2 = stats + 0;
  float* shift2 = stats + 128;

  // 1. prep: x/W1/W2 -> bf16, zero bcur+done + stat replicas
  k_prep<<<XCONV_B + 32, 256, 0, stream>>>(x, W1, W2, xb, W1b, W2b, bcur, reps);
  // 2. bin edges into fixed 32-row buckets (packed u32)
  k_bin0<<<BIN_BLOCKS, 256, 0, stream>>>(rows, cols, bcur, bbuf);
  // 3. FUSED per-bucket sort + gather aggregation + GEMM1 -> h1b, BN1 stats
  k_aggemm1<<<NBUCK, 256, 0, stream>>>(xb, eps, bcur, bbuf, W1b, b1, h1b,
                                       sum1r, sumsq1r);
  // 4. GEMM2 (BN1+ReLU on the fly) -> h2b, BN2 stats; last block collapses
  //    BN2 replicas -> scale2/shift2 (fence-free done-counter)
  k_gemm2<<<GEMM_B, 256, 0, stream>>>(h1b, sum1r, sumsq1r, g1, be1, W2b, b2,
                                      h2b, sum2r, sumsq2r, g2, be2,
                                      scale2, shift2, done);
  // 5. final BN2+ReLU -> fp32 out
  k_bnrelu<<<(NN * DD / 8) / 256, 256, 0, stream>>>(h2b, scale2, shift2, out);
}

// Round 3
// 209.189 us; speedup vs baseline: 1.2647x; 1.0183x over previous
//
#include <hip/hip_runtime.h>

#define NN 50000
#define EE 800000
#define DD 128
#define BN_EPS 1e-5f
#define XCONV_B 3125    // N*D/8/256
#define BIN_BLOCKS 200
#define BIN_EDGES 4000  // per block; 200*4000 == EE
#define NBUCK 3125      // 50000/16: 16-row buckets (exact, no partial bucket)
#define BROWS 16
#define BCAP 512        // bucket capacity (mean 256, +16 sigma headroom)
#define NREP 32         // BN-stat replica count
#define GEMM_B 782      // ceil(NN/64) for gemm2
#define LDA 136         // padded LDS A-tile stride (bf16): 272B -> 2-way banks

typedef __attribute__((ext_vector_type(8))) short bf16x8;
typedef __attribute__((ext_vector_type(4))) float f32x4;
typedef __attribute__((ext_vector_type(8))) unsigned short u16x8;

__device__ inline unsigned short f2bf(float f) {  // RNE fp32 -> bf16
  unsigned int u = __float_as_uint(f);
  u = (u + 0x7fffu + ((u >> 16) & 1u)) >> 16;
  return (unsigned short)u;
}
__device__ inline float bf2f(unsigned short b) {
  return __uint_as_float(((unsigned int)b) << 16);
}

// ---------------------------------------------------------------------------
// Memory plan (byte offsets into d_out, 25.6MB; scratch dead before k_bnrelu
// overwrites d_out with the fp32 result):
//   [0, +12.5KB)    bcur[NBUCK] bucket cursors + done[1] (gemm2 last-block)
//   [4.0M, 16.8M)   xb  = bf16(x)                  (dies after k_aggemm1)
//   [16.8M, 23.2M)  bbuf = u32[NBUCK*BCAP] packed (row&15)<<16|col
//   [23.28M,+32KB)  W1b; [23.36M,+32KB) W2b
//   [23.5M, +64KB)  reps: sum1[NREP][128] | sumsq1 | sum2 | sumsq2
// d_ws (25.6MB + 4KB): h1b | h2b | stats tail: scale2[128] | shift2[128]
// 5 dispatches. Lessons pinned: grid.sync ~100us/sync (R8); launch gap
// ~13us/dispatch (R7-R9); __threadfence() = per-wave L2 wb/inv flush storm
// (R12) -> fence-free done-counter; 4-wave 32-row aggemm blocks LOWERED
// resident blocks 4.4->2.6/CU, net -10% (R13). aggemm is concurrency-
// starved (42cy/edge vs ~10cy VALU floor, mem system needs only ~13
// loads-in-flight/CU): fix = 16-row buckets (3125 blocks, 2x resident
// waves) + row-PAIR gather (8 loads in flight/wave, 4 exposures not 16).
// ---------------------------------------------------------------------------

// K0: fused prep — x->bf16, W1->bf16, W2->bf16, zero bcur+done + stat replicas
__global__ __launch_bounds__(256) void k_prep(const float* __restrict__ x,
                                              const float* __restrict__ W1,
                                              const float* __restrict__ W2,
                                              unsigned short* __restrict__ xb,
                                              unsigned short* __restrict__ W1b,
                                              unsigned short* __restrict__ W2b,
                                              int* __restrict__ bcur,
                                              float* __restrict__ reps) {
  const int b = blockIdx.x;
  const int t = threadIdx.x;
  if (b < XCONV_B) {
    const int gid = b * 256 + t;
    const float4 v0 = ((const float4*)x)[gid * 2];
    const float4 v1 = ((const float4*)x)[gid * 2 + 1];
    ushort4 o0, o1;
    o0.x = f2bf(v0.x); o0.y = f2bf(v0.y); o0.z = f2bf(v0.z); o0.w = f2bf(v0.w);
    o1.x = f2bf(v1.x); o1.y = f2bf(v1.y); o1.z = f2bf(v1.z); o1.w = f2bf(v1.w);
    ((ushort4*)xb)[gid * 2] = o0;
    ((ushort4*)xb)[gid * 2 + 1] = o1;
    if (gid <= NBUCK) bcur[gid] = 0;  // includes done counter at [NBUCK]
    if (gid < 4 * NREP * DD) reps[gid] = 0.0f;  // 16384 floats
  } else if (b < XCONV_B + 16) {
    const int gid = (b - XCONV_B) * 256 + t;
    const float4 v = ((const float4*)W1)[gid];
    ushort4 o;
    o.x = f2bf(v.x); o.y = f2bf(v.y); o.z = f2bf(v.z); o.w = f2bf(v.w);
    ((ushort4*)W1b)[gid] = o;
  } else {
    const int gid = (b - XCONV_B - 16) * 256 + t;
    const float4 v = ((const float4*)W2)[gid];
    ushort4 o;
    o.x = f2bf(v.x); o.y = f2bf(v.y); o.z = f2bf(v.z); o.w = f2bf(v.w);
    ((ushort4*)W2b)[gid] = o;
  }
}

// K1: bin edges into fixed-capacity 16-row buckets (block-private segments
// via one global reservation per bucket — HBM write amp stays 1x).
__global__ __launch_bounds__(256) void k_bin0(const int* __restrict__ rows,
                                              const int* __restrict__ cols,
                                              int* __restrict__ bcur,
                                              unsigned int* __restrict__ bbuf) {
  __shared__ int hist[NBUCK];   // 12.5KB
  __shared__ int lbase[NBUCK];  // 12.5KB
  const int t = threadIdx.x;
  for (int i = t; i < NBUCK; i += 256) hist[i] = 0;
  __syncthreads();
  const int e0 = blockIdx.x * BIN_EDGES;
  int er[16], ec[16];
#pragma unroll
  for (int i = 0; i < 16; ++i) {
    const int idx = t + i * 256;
    if (idx < BIN_EDGES) {
      er[i] = rows[e0 + idx];
      ec[i] = cols[e0 + idx];
      atomicAdd(&hist[er[i] >> 4], 1);
    }
  }
  __syncthreads();
  for (int i = t; i < NBUCK; i += 256) {
    const int c = hist[i];
    lbase[i] = (c > 0) ? atomicAdd(&bcur[i], c) : 0;
    hist[i] = 0;  // reuse as local placement cursor
  }
  __syncthreads();
#pragma unroll
  for (int i = 0; i < 16; ++i) {
    const int idx = t + i * 256;
    if (idx < BIN_EDGES) {
      const int bk = er[i] >> 4;
      const int lp = lbase[bk] + atomicAdd(&hist[bk], 1);
      if (lp < BCAP)  // statistically impossible overflow; memory-safety clamp
        bbuf[(size_t)bk * BCAP + lp] =
            ((unsigned)(er[i] & 15) << 16) | (unsigned)ec[i];
    }
  }
}

// K2: FUSED per-bucket aggregation + GEMM1. Block = bucket b = rows
// [16b,16b+16), 128 threads (2 waves). Phase A: LDS counting sort (wave-0
// shfl scan over 16 counts) + row-PAIR gather: each wave owns 8 rows,
// processes them 2 at a time with dual accumulators -> 8 gather loads in
// flight per wave (4 latency exposures/wave instead of 16). Phase B: MFMA
// GEMM 16x128 (A from LDS, B=W1b from global), waves split columns 2x64;
// epilogue writes h1b + BN1 replica stats straight from registers.
__global__ __launch_bounds__(128) void k_aggemm1(
    const unsigned short* __restrict__ xb, const float* __restrict__ eps,
    const int* __restrict__ bcnt, const unsigned int* __restrict__ bbuf,
    const unsigned short* __restrict__ W, const float* __restrict__ bias,
    unsigned short* __restrict__ outb, float* __restrict__ sum1r,
    float* __restrict__ sumsq1r) {
  __shared__ unsigned short scols[BCAP];      // 1KB sorted col ids
  __shared__ unsigned short sA[BROWS * LDA];  // 4.25KB padded A tile (bf16)
  __shared__ int rcnt[BROWS];
  __shared__ int roff[BROWS + 1];
  const int t = threadIdx.x;
  const int bk = blockIdx.x;
  const int wv = t >> 6;       // 0..1
  const int lane = t & 63;
  const int sub = lane >> 4;   // 0..3 (== quad in phase B)
  const int l16 = lane & 15;

  int n = bcnt[bk];
  n = n < BCAP ? n : BCAP;
  if (t < BROWS) rcnt[t] = 0;
  __syncthreads();

  // ---- phase A1: load bucket entries + per-row count
  unsigned int ent[4];
  int nl = 0;
  for (int i = t; i < n; i += 128) {
    const unsigned int e = bbuf[(size_t)bk * BCAP + i];
    ent[nl++] = e;
    atomicAdd(&rcnt[e >> 16], 1);
  }
  __syncthreads();
  // exclusive scan of 16 row-counts — wave 0 lanes 0..15, shfl-based
  if (t < BROWS) {
    int v = rcnt[t];
#pragma unroll
    for (int off = 1; off < BROWS; off <<= 1) {
      const int u = __shfl_up(v, off);
      if (lane >= off) v += u;
    }
    roff[t] = v - rcnt[t];
    if (t == BROWS - 1) roff[BROWS] = v;
    rcnt[t] = 0;  // reuse as placement cursor (wave-coherent)
  }
  __syncthreads();
  // place col ids row-sorted
  for (int i = 0; i < nl; ++i) {
    const int r = ent[i] >> 16;
    const int pos = roff[r] + atomicAdd(&rcnt[r], 1);
    scols[pos] = (unsigned short)(ent[i] & 0xffffu);
  }
  __syncthreads();

  // ---- phase A2: row-pair gather; wave wv owns rows {wv, wv+2, .., wv+14}
  {
    const float s = 1.0f + eps[0];
#pragma unroll
    for (int rr = 0; rr < 4; ++rr) {
      const int r0 = wv + rr * 4;
      const int r1 = r0 + 2;
      float a0[8], a1[8];
#pragma unroll
      for (int j = 0; j < 8; ++j) { a0[j] = 0.f; a1[j] = 0.f; }
      // self rows: sub0 loads node r0, sub1 loads node r1 (scaled by 1+eps)
      if (sub < 2) {
        const int selfrow = bk * BROWS + (sub == 0 ? r0 : r1);
        const u16x8 a = *(const u16x8*)(xb + (size_t)selfrow * DD + l16 * 8);
        if (sub == 0) {
#pragma unroll
          for (int j = 0; j < 8; ++j) a0[j] = s * bf2f(a[j]);
        } else {
#pragma unroll
          for (int j = 0; j < 8; ++j) a1[j] = s * bf2f(a[j]);
        }
      }
      int i0 = roff[r0] + sub;
      const int E0 = roff[r0 + 1];
      int i1 = roff[r1] + sub;
      const int E1 = roff[r1 + 1];
      // interleaved dual 4-deep pipeline: 8 loads in flight per wave
      while (i0 + 12 < E0 && i1 + 12 < E1) {
        const int u0 = scols[i0], u1 = scols[i0 + 4];
        const int u2 = scols[i0 + 8], u3 = scols[i0 + 12];
        const int v0 = scols[i1], v1 = scols[i1 + 4];
        const int v2 = scols[i1 + 8], v3 = scols[i1 + 12];
        const u16x8 pa = *(const u16x8*)(xb + (size_t)u0 * DD + l16 * 8);
        const u16x8 pb = *(const u16x8*)(xb + (size_t)u1 * DD + l16 * 8);
        const u16x8 pc = *(const u16x8*)(xb + (size_t)u2 * DD + l16 * 8);
        const u16x8 pd = *(const u16x8*)(xb + (size_t)u3 * DD + l16 * 8);
        const u16x8 qa = *(const u16x8*)(xb + (size_t)v0 * DD + l16 * 8);
        const u16x8 qb = *(const u16x8*)(xb + (size_t)v1 * DD + l16 * 8);
        const u16x8 qc = *(const u16x8*)(xb + (size_t)v2 * DD + l16 * 8);
        const u16x8 qd = *(const u16x8*)(xb + (size_t)v3 * DD + l16 * 8);
#pragma unroll
        for (int j = 0; j < 8; ++j) {
          a0[j] += (bf2f(pa[j]) + bf2f(pb[j])) + (bf2f(pc[j]) + bf2f(pd[j]));
          a1[j] += (bf2f(qa[j]) + bf2f(qb[j])) + (bf2f(qc[j]) + bf2f(qd[j]));
        }
        i0 += 16;
        i1 += 16;
      }
      // finish row r0
      for (; i0 + 12 < E0; i0 += 16) {
        const int u0 = scols[i0], u1 = scols[i0 + 4];
        const int u2 = scols[i0 + 8], u3 = scols[i0 + 12];
        const u16x8 pa = *(const u16x8*)(xb + (size_t)u0 * DD + l16 * 8);
        const u16x8 pb = *(const u16x8*)(xb + (size_t)u1 * DD + l16 * 8);
        const u16x8 pc = *(const u16x8*)(xb + (size_t)u2 * DD + l16 * 8);
        const u16x8 pd = *(const u16x8*)(xb + (size_t)u3 * DD + l16 * 8);
#pragma unroll
        for (int j = 0; j < 8; ++j)
          a0[j] += (bf2f(pa[j]) + bf2f(pb[j])) + (bf2f(pc[j]) + bf2f(pd[j]));
      }
      for (; i0 + 4 < E0; i0 += 8) {
        const int u0 = scols[i0], u1 = scols[i0 + 4];
        const u16x8 pa = *(const u16x8*)(xb + (size_t)u0 * DD + l16 * 8);
        const u16x8 pb = *(const u16x8*)(xb + (size_t)u1 * DD + l16 * 8);
#pragma unroll
        for (int j = 0; j < 8; ++j) a0[j] += bf2f(pa[j]) + bf2f(pb[j]);
      }
      if (i0 < E0) {
        const int u0 = scols[i0];
        const u16x8 pa = *(const u16x8*)(xb + (size_t)u0 * DD + l16 * 8);
#pragma unroll
        for (int j = 0; j < 8; ++j) a0[j] += bf2f(pa[j]);
      }
      // finish row r1
      for (; i1 + 12 < E1; i1 += 16) {
        const int v0 = scols[i1], v1 = scols[i1 + 4];
        const int v2 = scols[i1 + 8], v3 = scols[i1 + 12];
        const u16x8 qa = *(const u16x8*)(xb + (size_t)v0 * DD + l16 * 8);
        const u16x8 qb = *(const u16x8*)(xb + (size_t)v1 * DD + l16 * 8);
        const u16x8 qc = *(const u16x8*)(xb + (size_t)v2 * DD + l16 * 8);
        const u16x8 qd = *(const u16x8*)(xb + (size_t)v3 * DD + l16 * 8);
#pragma unroll
        for (int j = 0; j < 8; ++j)
          a1[j] += (bf2f(qa[j]) + bf2f(qb[j])) + (bf2f(qc[j]) + bf2f(qd[j]));
      }
      for (; i1 + 4 < E1; i1 += 8) {
        const int v0 = scols[i1], v1 = scols[i1 + 4];
        const u16x8 qa = *(const u16x8*)(xb + (size_t)v0 * DD + l16 * 8);
        const u16x8 qb = *(const u16x8*)(xb + (size_t)v1 * DD + l16 * 8);
#pragma unroll
        for (int j = 0; j < 8; ++j) a1[j] += bf2f(qa[j]) + bf2f(qb[j]);
      }
      if (i1 < E1) {
        const int v0 = scols[i1];
        const u16x8 qa = *(const u16x8*)(xb + (size_t)v0 * DD + l16 * 8);
#pragma unroll
        for (int j = 0; j < 8; ++j) a1[j] += bf2f(qa[j]);
      }
      // cross-sub reduce + LDS write (both rows in parallel: sub0/sub1)
#pragma unroll
      for (int j = 0; j < 8; ++j) {
        a0[j] += __shfl_xor(a0[j], 16);
        a0[j] += __shfl_xor(a0[j], 32);
        a1[j] += __shfl_xor(a1[j], 16);
        a1[j] += __shfl_xor(a1[j], 32);
      }
      if (sub < 2) {
        u16x8 o;
        if (sub == 0) {
#pragma unroll
          for (int j = 0; j < 8; ++j) o[j] = f2bf(a0[j]);
          *(u16x8*)(&sA[r0 * LDA + l16 * 8]) = o;
        } else {
#pragma unroll
          for (int j = 0; j < 8; ++j) o[j] = f2bf(a1[j]);
          *(u16x8*)(&sA[r1 * LDA + l16 * 8]) = o;
        }
      }
    }
  }
  __syncthreads();

  // ---- phase B: MFMA GEMM 16x128; wave wv owns cols [wv*64, wv*64+64)
  f32x4 acc[4];
#pragma unroll
  for (int nn = 0; nn < 4; ++nn) acc[nn] = (f32x4){0.f, 0.f, 0.f, 0.f};
#pragma unroll
  for (int kk = 0; kk < 4; ++kk) {
    const bf16x8 af = *(const bf16x8*)(&sA[l16 * LDA + kk * 32 + sub * 8]);
#pragma unroll
    for (int nn = 0; nn < 4; ++nn) {
      const bf16x8 bf = *(const bf16x8*)(
          W + (size_t)(wv * 64 + nn * 16 + l16) * DD + sub * 8 + kk * 32);
      acc[nn] = __builtin_amdgcn_mfma_f32_16x16x32_bf16(af, bf, acc[nn], 0, 0, 0);
    }
  }
  // epilogue: rows exact (NN % 16 == 0), stats direct from registers
  const int orow0 = bk * BROWS + sub * 4;
  const int rep = (bk & (NREP - 1)) * DD;
#pragma unroll
  for (int nn = 0; nn < 4; ++nn) {
    const int col = wv * 64 + nn * 16 + l16;
    const float bv = bias[col];
    float sv = 0.f, qv = 0.f;
#pragma unroll
    for (int r = 0; r < 4; ++r) {
      const float o = acc[nn][r] + bv;
      outb[(size_t)(orow0 + r) * DD + col] = f2bf(o);
      sv += o; qv += o * o;
    }
    sv += __shfl_xor(sv, 16); qv += __shfl_xor(qv, 16);
    sv += __shfl_xor(sv, 32); qv += __shfl_xor(qv, 32);
    if (sub == 0) {
      atomicAdd(&sum1r[rep + col], sv);
      atomicAdd(&sumsq1r[rep + col], qv);
    }
  }
}

// ---------------------------------------------------------------------------
// GEMM2: collapse sum1 replicas -> BN1 scale/shift in-block; A=relu(BN1(h1b))
// on the fly; out = h2b bf16; BN2 stats into replicas. The LAST block to
// finish (done-counter) collapses the BN2 replicas into scale2/shift2 —
// replaces the former k_bnstats2 dispatch (~13us launch gap saved).
// FENCE-FREE protocol (R12 lesson: __threadfence() = per-wave L2 wb/inv
// flush storm, 89us @ 3% VALUBusy): replica updates are device-scope atomic
// RMWs completing at the coherence point; __syncthreads() drains vmcnt(0)
// before s_barrier, so tid0's done-RMW is HW-ordered after this block's
// replica RMWs; the last block reads replicas with agent-scope atomic loads.
// ---------------------------------------------------------------------------
__global__ __launch_bounds__(256) void k_gemm2(const unsigned short* __restrict__ A,
                                               const float* __restrict__ sum1r,
                                               const float* __restrict__ sumsq1r,
                                               const float* __restrict__ gamma,
                                               const float* __restrict__ beta,
                                               const unsigned short* __restrict__ W,
                                               const float* __restrict__ bias,
                                               unsigned short* __restrict__ outb,
                                               float* __restrict__ sum2r,
                                               float* __restrict__ sumsq2r,
                                               const float* __restrict__ gamma2,
                                               const float* __restrict__ beta2,
                                               float* __restrict__ scale2,
                                               float* __restrict__ shift2,
                                               int* __restrict__ done) {
  __shared__ float lsc[DD];
  __shared__ float lsh[DD];
  __shared__ float bsum[DD];
  __shared__ float bsq[DD];
  __shared__ int amlast;
  const int tid = threadIdx.x;
  const int wv = tid >> 6;
  const int lane = tid & 63;
  const int quad = lane >> 4;
  const int l16 = lane & 15;
  if (tid < DD) {
    float sm = 0.f, qm = 0.f;
#pragma unroll
    for (int r = 0; r < NREP; ++r) {
      sm += sum1r[r * DD + tid];
      qm += sumsq1r[r * DD + tid];
    }
    const float inv_n = 1.0f / (float)NN;
    const float mean = sm * inv_n;
    const float var = qm * inv_n - mean * mean;
    const float s = gamma[tid] * rsqrtf(var + BN_EPS);
    lsc[tid] = s;
    lsh[tid] = beta[tid] - mean * s;
    bsum[tid] = 0.f;
    bsq[tid] = 0.f;
  }
  __syncthreads();

  const int rowbase = blockIdx.x * 64 + wv * 16 + l16;
  const int arow = rowbase < NN ? rowbase : NN - 1;
  const unsigned short* aptr = A + (size_t)arow * DD + quad * 8;

  f32x4 acc[8];
#pragma unroll
  for (int n = 0; n < 8; ++n) acc[n] = (f32x4){0.f, 0.f, 0.f, 0.f};
#pragma unroll
  for (int kk = 0; kk < 4; ++kk) {
    const int kbase = kk * 32 + quad * 8;
    const u16x8 a = *(const u16x8*)(aptr + kk * 32);
    const float4 s0 = *(const float4*)&lsc[kbase];
    const float4 s1 = *(const float4*)&lsc[kbase + 4];
    const float4 h0 = *(const float4*)&lsh[kbase];
    const float4 h1 = *(const float4*)&lsh[kbase + 4];
    bf16x8 af;
    af[0] = (short)f2bf(fmaxf(fmaf(s0.x, bf2f(a[0]), h0.x), 0.f));
    af[1] = (short)f2bf(fmaxf(fmaf(s0.y, bf2f(a[1]), h0.y), 0.f));
    af[2] = (short)f2bf(fmaxf(fmaf(s0.z, bf2f(a[2]), h0.z), 0.f));
    af[3] = (short)f2bf(fmaxf(fmaf(s0.w, bf2f(a[3]), h0.w), 0.f));
    af[4] = (short)f2bf(fmaxf(fmaf(s1.x, bf2f(a[4]), h1.x), 0.f));
    af[5] = (short)f2bf(fmaxf(fmaf(s1.y, bf2f(a[5]), h1.y), 0.f));
    af[6] = (short)f2bf(fmaxf(fmaf(s1.z, bf2f(a[6]), h1.z), 0.f));
    af[7] = (short)f2bf(fmaxf(fmaf(s1.w, bf2f(a[7]), h1.w), 0.f));
#pragma unroll
    for (int n = 0; n < 8; ++n) {
      const bf16x8 bf =
          *(const bf16x8*)(W + (size_t)(n * 16 + l16) * DD + kbase);
      acc[n] = __builtin_amdgcn_mfma_f32_16x16x32_bf16(af, bf, acc[n], 0, 0, 0);
    }
  }
  const int orow0 = blockIdx.x * 64 + wv * 16 + quad * 4;
#pragma unroll
  for (int n = 0; n < 8; ++n) {
    const int col = n * 16 + l16;
    const float bv = bias[col];
    float sv = 0.f, qv = 0.f;
#pragma unroll
    for (int r = 0; r < 4; ++r) {
      const int row = orow0 + r;
      if (row < NN) {
        const float o = acc[n][r] + bv;
        outb[(size_t)row * DD + col] = f2bf(o);
        sv += o; qv += o * o;
      }
    }
    sv += __shfl_xor(sv, 16); qv += __shfl_xor(qv, 16);
    sv += __shfl_xor(sv, 32); qv += __shfl_xor(qv, 32);
    if (quad == 0) { atomicAdd(&bsum[col], sv); atomicAdd(&bsq[col], qv); }
  }
  __syncthreads();
  if (tid < DD) {
    const int rep = (blockIdx.x & (NREP - 1)) * DD;
    atomicAdd(&sum2r[rep + tid], bsum[tid]);
    atomicAdd(&sumsq2r[rep + tid], bsq[tid]);
  }

  // ---- last-block BN2 replica collapse (fence-free; see header comment).
  __syncthreads();
  if (tid == 0) amlast = (atomicAdd(done, 1) == GEMM_B - 1) ? 1 : 0;
  __syncthreads();
  if (amlast) {
    if (tid < DD) {
      float sm = 0.f, qm = 0.f;
#pragma unroll
      for (int r = 0; r < NREP; ++r) {
        sm += __hip_atomic_load(&sum2r[r * DD + tid], __ATOMIC_RELAXED,
                                __HIP_MEMORY_SCOPE_AGENT);
        qm += __hip_atomic_load(&sumsq2r[r * DD + tid], __ATOMIC_RELAXED,
                                __HIP_MEMORY_SCOPE_AGENT);
      }
      const float inv_n = 1.0f / (float)NN;
      const float mean = sm * inv_n;
      const float var = qm * inv_n - mean * mean;
      const float sc = gamma2[tid] * rsqrtf(var + BN_EPS);
      scale2[tid] = sc;
      shift2[tid] = beta2[tid] - mean * sc;
    }
  }
}

// K4: final BN2 + ReLU -> fp32 out
__global__ __launch_bounds__(256) void k_bnrelu(const unsigned short* __restrict__ in,
                                                const float* __restrict__ scale,
                                                const float* __restrict__ shift,
                                                float* __restrict__ out) {
  __shared__ float lsc[DD];
  __shared__ float lsh[DD];
  const int t = threadIdx.x;
  if (t < DD) {
    lsc[t] = scale[t];
    lsh[t] = shift[t];
  }
  __syncthreads();
  const int gid = blockIdx.x * 256 + t;
  const int c = (gid & 15) * 8;
  const u16x8 a = ((const u16x8*)in)[gid];
  const float4 sc0 = *(const float4*)&lsc[c];
  const float4 sc1 = *(const float4*)&lsc[c + 4];
  const float4 sh0 = *(const float4*)&lsh[c];
  const float4 sh1 = *(const float4*)&lsh[c + 4];
  float4 o0, o1;
  o0.x = fmaxf(fmaf(sc0.x, bf2f(a[0]), sh0.x), 0.f);
  o0.y = fmaxf(fmaf(sc0.y, bf2f(a[1]), sh0.y), 0.f);
  o0.z = fmaxf(fmaf(sc0.z, bf2f(a[2]), sh0.z), 0.f);
  o0.w = fmaxf(fmaf(sc0.w, bf2f(a[3]), sh0.w), 0.f);
  o1.x = fmaxf(fmaf(sc1.x, bf2f(a[4]), sh1.x), 0.f);
  o1.y = fmaxf(fmaf(sc1.y, bf2f(a[5]), sh1.y), 0.f);
  o1.z = fmaxf(fmaf(sc1.z, bf2f(a[6]), sh1.z), 0.f);
  o1.w = fmaxf(fmaf(sc1.w, bf2f(a[7]), sh1.w), 0.f);
  ((float4*)out)[gid * 2] = o0;
  ((float4*)out)[gid * 2 + 1] = o1;
}

// ---------------------------------------------------------------------------
extern "C" void kernel_launch(void* const* d_in, const int* in_sizes, int n_in,
                              void* d_out, int out_size, void* d_ws, size_t ws_size,
                              hipStream_t stream) {
  const float* x = (const float*)d_in[0];
  const int* ei = (const int*)d_in[1];
  const float* eps = (const float*)d_in[2];
  const float* W1 = (const float*)d_in[3];
  const float* b1 = (const float*)d_in[4];
  const float* g1 = (const float*)d_in[5];
  const float* be1 = (const float*)d_in[6];
  const float* W2 = (const float*)d_in[7];
  const float* b2 = (const float*)d_in[8];
  const float* g2 = (const float*)d_in[9];
  const float* be2 = (const float*)d_in[10];
  float* out = (float*)d_out;

  const int* rows = ei;
  const int* cols = ei + EE;

  // d_out scratch (dead before k_bnrelu writes d_out)
  int* bcur = (int*)d_out;                                  // NBUCK ints + done
  unsigned short* xb = (unsigned short*)d_out + 2000000;    // byte 4.0M
  unsigned int* bbuf = (unsigned int*)((char*)d_out + 16800000);  // 6.4MB
  unsigned short* W1b = (unsigned short*)d_out + 11640000;  // byte 23.28M
  unsigned short* W2b = (unsigned short*)d_out + 11680000;  // byte 23.36M
  float* reps = (float*)d_out + 5875000;                    // byte 23.5M, 64KB
  float* sum1r = reps;
  float* sumsq1r = reps + NREP * DD;
  float* sum2r = reps + 2 * NREP * DD;
  float* sumsq2r = reps + 3 * NREP * DD;
  int* done = bcur + NBUCK;

  unsigned short* h1b = (unsigned short*)d_ws;        // aggemm1 out
  unsigned short* h2b = h1b + (size_t)NN * DD;        // gemm2 out
  float* stats = (float*)(h1b + (size_t)2 * NN * DD); // 4KB tail of d_ws
  float* scale2 = stats + 0;
  float* shift2 = stats + 128;

  // 1. prep: x/W1/W2 -> bf16, zero bcur+done + stat replicas
  k_prep<<<XCONV_B + 32, 256, 0, stream>>>(x, W1, W2, xb, W1b, W2b, bcur, reps);
  // 2. bin edges into fixed 16-row buckets (packed u32)
  k_bin0<<<BIN_BLOCKS, 256, 0, stream>>>(rows, cols, bcur, bbuf);
  // 3. FUSED per-bucket sort + gather aggregation + GEMM1 -> h1b, BN1 stats
  k_aggemm1<<<NBUCK, 128, 0, stream>>>(xb, eps, bcur, bbuf, W1b, b1, h1b,
                                       sum1r, sumsq1r);
  // 4. GEMM2 (BN1+ReLU on the fly) -> h2b, BN2 stats; last block collapses
  //    BN2 replicas -> scale2/shift2 (fence-free done-counter)
  k_gemm2<<<GEMM_B, 256, 0, stream>>>(h1b, sum1r, sumsq1r, g1, be1, W2b, b2,
                                      h2b, sum2r, sumsq2r, g2, be2,
                                      scale2, shift2, done);
  // 5. final BN2+ReLU -> fp32 out
  k_bnrelu<<<(NN * DD / 8) / 256, 256, 0, stream>>>(h2b, scale2, shift2, out);
}

// Round 4
// 204.118 us; speedup vs baseline: 1.2961x; 1.0248x over previous
//
#include <hip/hip_runtime.h>

#define NN 50000
#define EE 800000
#define DD 128
#define BN_EPS 1e-5f
#define XCONV_B 3125    // N*D/8/256
#define BIN_BLOCKS 200
#define BIN_EDGES 4000  // per block; 200*4000 == EE
#define NBUCK 3125      // 50000/16: 16-row buckets (exact)
#define BROWS 16
#define BCAP 512        // bucket capacity (mean 256, +16 sigma headroom)
#define NREP 32         // BN-stat replica count
#define MLP_B 391       // ceil(50000/128) fused-MLP blocks
#define LDA 136         // padded LDS tile stride (bf16)

typedef __attribute__((ext_vector_type(8))) short bf16x8;
typedef __attribute__((ext_vector_type(4))) float f32x4;
typedef __attribute__((ext_vector_type(8))) unsigned short u16x8;

__device__ inline unsigned short f2bf(float f) {  // RNE fp32 -> bf16
  unsigned int u = __float_as_uint(f);
  u = (u + 0x7fffu + ((u >> 16) & 1u)) >> 16;
  return (unsigned short)u;
}
__device__ inline float bf2f(unsigned short b) {
  return __uint_as_float(((unsigned int)b) << 16);
}
__device__ inline float ldw(const float* p) {
  return __hip_atomic_load(p, __ATOMIC_RELAXED, __HIP_MEMORY_SCOPE_AGENT);
}
__device__ inline void stw(float* p, float v) {
  __hip_atomic_store(p, v, __ATOMIC_RELAXED, __HIP_MEMORY_SCOPE_AGENT);
}

// ---------------------------------------------------------------------------
// R14 redesign. Lessons pinned: launch gap ~13-20us/dispatch (R7-R9); grid
// sync 100us (R8); __threadfence = L2 wb/inv storm (R12); occupancy hard-caps
// at ~9-10 waves/CU for the random gather REGARDLESS of grid/block shape
// (R11/R13/R14) -> diagnosis: per-XCD L2 (4MB) thrashes on 12.8MB random
// gather, L2 miss-concurrency saturates; more waves don't help.
// Fixes here:
//  * xq column-blocked layout: 4 slices x 3.2MB; aggregation split into 4
//    passes (blockIdx = pass*NBUCK + bucket so resident blocks cluster in
//    one pass) -> per-XCD L2-resident slice -> ~95% L2 hit.
//  * 8-lane row groups: each group owns one row x 32 cols; NO cross-lane
//    reduce, 4-deep load pipeline, results written straight to agg (d_ws).
//  * ONE fused MLP kernel (391 blocks x 256): GEMM1 -> BN1 stats -> spin ->
//    BN1+ReLU -> GEMM2 -> BN2 stats -> spin -> BN2+ReLU -> fp32 out.
//    Spin-broadcast is capacity-safe: __launch_bounds__(256,2) + 36KB LDS
//    guarantee >=2 blocks/CU co-resident (512 slots >= 391 blocks), valid
//    even under the observed 9-wave/CU ceiling. Fence-free: device-scope
//    atomics + __syncthreads() vmcnt drains (R12 protocol).
//  * 4 dispatches (was 5); h1b/h2b round-trips and k_bnrelu eliminated.
// d_out scratch: bcur | xq(4.0M..16.8M) | bbuf(16.8M..23.2M) | W1b,W2b | reps
// (all dead before the final out write: out happens only after flag2, which
// requires every block past its last scratch read).
// d_ws: agg bf16 [0,12.8M) | scale1,shift1,scale2,shift2 | syncw[4].
// ---------------------------------------------------------------------------

// K0: fused prep — x->bf16 column-blocked xq, W1b, W2b, zero bcur/reps/syncw
__global__ __launch_bounds__(256) void k_prep(const float* __restrict__ x,
                                              const float* __restrict__ W1,
                                              const float* __restrict__ W2,
                                              unsigned short* __restrict__ xq,
                                              unsigned short* __restrict__ W1b,
                                              unsigned short* __restrict__ W2b,
                                              int* __restrict__ bcur,
                                              float* __restrict__ reps,
                                              int* __restrict__ syncw) {
  const int b = blockIdx.x;
  const int t = threadIdx.x;
  if (b < XCONV_B) {
    const int gid = b * 256 + t;
    const float4 v0 = ((const float4*)x)[gid * 2];
    const float4 v1 = ((const float4*)x)[gid * 2 + 1];
    ushort4 o0, o1;
    o0.x = f2bf(v0.x); o0.y = f2bf(v0.y); o0.z = f2bf(v0.z); o0.w = f2bf(v0.w);
    o1.x = f2bf(v1.x); o1.y = f2bf(v1.y); o1.z = f2bf(v1.z); o1.w = f2bf(v1.w);
    const int node = gid >> 4;
    const int c0 = (gid & 15) * 8;
    const size_t dst = (size_t)(c0 >> 5) * (NN * 32) + node * 32 + (c0 & 31);
    *(ushort4*)(xq + dst) = o0;
    *(ushort4*)(xq + dst + 4) = o1;
    if (gid < NBUCK) bcur[gid] = 0;
    if (gid < 4 * NREP * DD) reps[gid] = 0.0f;
    if (gid < 4) syncw[gid] = 0;  // done1, flag1, done2, flag2
  } else if (b < XCONV_B + 16) {
    const int gid = (b - XCONV_B) * 256 + t;
    const float4 v = ((const float4*)W1)[gid];
    ushort4 o;
    o.x = f2bf(v.x); o.y = f2bf(v.y); o.z = f2bf(v.z); o.w = f2bf(v.w);
    ((ushort4*)W1b)[gid] = o;
  } else {
    const int gid = (b - XCONV_B - 16) * 256 + t;
    const float4 v = ((const float4*)W2)[gid];
    ushort4 o;
    o.x = f2bf(v.x); o.y = f2bf(v.y); o.z = f2bf(v.z); o.w = f2bf(v.w);
    ((ushort4*)W2b)[gid] = o;
  }
}

// K1: bin edges into fixed-capacity 16-row buckets (unchanged, proven)
__global__ __launch_bounds__(256) void k_bin0(const int* __restrict__ rows,
                                              const int* __restrict__ cols,
                                              int* __restrict__ bcur,
                                              unsigned int* __restrict__ bbuf) {
  __shared__ int hist[NBUCK];
  __shared__ int lbase[NBUCK];
  const int t = threadIdx.x;
  for (int i = t; i < NBUCK; i += 256) hist[i] = 0;
  __syncthreads();
  const int e0 = blockIdx.x * BIN_EDGES;
  int er[16], ec[16];
#pragma unroll
  for (int i = 0; i < 16; ++i) {
    const int idx = t + i * 256;
    if (idx < BIN_EDGES) {
      er[i] = rows[e0 + idx];
      ec[i] = cols[e0 + idx];
      atomicAdd(&hist[er[i] >> 4], 1);
    }
  }
  __syncthreads();
  for (int i = t; i < NBUCK; i += 256) {
    const int c = hist[i];
    lbase[i] = (c > 0) ? atomicAdd(&bcur[i], c) : 0;
    hist[i] = 0;
  }
  __syncthreads();
#pragma unroll
  for (int i = 0; i < 16; ++i) {
    const int idx = t + i * 256;
    if (idx < BIN_EDGES) {
      const int bk = er[i] >> 4;
      const int lp = lbase[bk] + atomicAdd(&hist[bk], 1);
      if (lp < BCAP)
        bbuf[(size_t)bk * BCAP + lp] =
            ((unsigned)(er[i] & 15) << 16) | (unsigned)ec[i];
    }
  }
}

// K2: pass-sliced aggregation. Block (q,bk) gathers col-slice q (32 cols,
// 3.2MB L2-resident) for bucket bk. 16 groups of 8 lanes; group g owns row g:
// contiguous sorted edge walk, 4-deep pipeline, 4 fp32 accs/lane, no shuffle.
__global__ __launch_bounds__(128) void k_agg(
    const unsigned short* __restrict__ xq, const float* __restrict__ eps,
    const int* __restrict__ bcnt, const unsigned int* __restrict__ bbuf,
    unsigned short* __restrict__ aggb) {
  __shared__ unsigned short scols[BCAP];
  __shared__ int rcnt[BROWS];
  __shared__ int roff[BROWS + 1];
  const int t = threadIdx.x;
  const int id = blockIdx.x;
  const int q = id / NBUCK;        // consecutive ids share a pass
  const int bk = id - q * NBUCK;

  int n = bcnt[bk];
  n = n < BCAP ? n : BCAP;
  if (t < BROWS) rcnt[t] = 0;
  __syncthreads();

  // counting sort by row (proven R3 code)
  unsigned int ent[4];
  int nl = 0;
  for (int i = t; i < n; i += 128) {
    const unsigned int e = bbuf[(size_t)bk * BCAP + i];
    ent[nl++] = e;
    atomicAdd(&rcnt[e >> 16], 1);
  }
  __syncthreads();
  if (t < BROWS) {
    int v = rcnt[t];
#pragma unroll
    for (int off = 1; off < BROWS; off <<= 1) {
      const int u = __shfl_up(v, off);
      if (t >= off) v += u;
    }
    roff[t] = v - rcnt[t];
    if (t == BROWS - 1) roff[BROWS] = v;
    rcnt[t] = 0;
  }
  __syncthreads();
  for (int i = 0; i < nl; ++i) {
    const int r = ent[i] >> 16;
    const int pos = roff[r] + atomicAdd(&rcnt[r], 1);
    scols[pos] = (unsigned short)(ent[i] & 0xffffu);
  }
  __syncthreads();

  // gather: group g (8 lanes) owns row g, cols q*32 + l8*4 .. +3
  const int g = t >> 3;
  const int l8 = t & 3 | ((t & 7) & ~3);  // == t & 7
  const unsigned short* xqq = xq + (size_t)q * (NN * 32);
  const float s = 1.0f + eps[0];
  const int v = bk * BROWS + g;
  const ushort4 sv4 = *(const ushort4*)(xqq + (size_t)v * 32 + (t & 7) * 4);
  float a0 = s * bf2f(sv4.x);
  float a1 = s * bf2f(sv4.y);
  float a2 = s * bf2f(sv4.z);
  float a3 = s * bf2f(sv4.w);
  int i = roff[g];
  const int E = roff[g + 1];
  const int lo = (t & 7) * 4;
  for (; i + 3 < E; i += 4) {
    const int u0 = scols[i], u1 = scols[i + 1];
    const int u2 = scols[i + 2], u3 = scols[i + 3];
    const ushort4 p0 = *(const ushort4*)(xqq + (size_t)u0 * 32 + lo);
    const ushort4 p1 = *(const ushort4*)(xqq + (size_t)u1 * 32 + lo);
    const ushort4 p2 = *(const ushort4*)(xqq + (size_t)u2 * 32 + lo);
    const ushort4 p3 = *(const ushort4*)(xqq + (size_t)u3 * 32 + lo);
    a0 += (bf2f(p0.x) + bf2f(p1.x)) + (bf2f(p2.x) + bf2f(p3.x));
    a1 += (bf2f(p0.y) + bf2f(p1.y)) + (bf2f(p2.y) + bf2f(p3.y));
    a2 += (bf2f(p0.z) + bf2f(p1.z)) + (bf2f(p2.z) + bf2f(p3.z));
    a3 += (bf2f(p0.w) + bf2f(p1.w)) + (bf2f(p2.w) + bf2f(p3.w));
  }
  for (; i + 1 < E; i += 2) {
    const int u0 = scols[i], u1 = scols[i + 1];
    const ushort4 p0 = *(const ushort4*)(xqq + (size_t)u0 * 32 + lo);
    const ushort4 p1 = *(const ushort4*)(xqq + (size_t)u1 * 32 + lo);
    a0 += bf2f(p0.x) + bf2f(p1.x);
    a1 += bf2f(p0.y) + bf2f(p1.y);
    a2 += bf2f(p0.z) + bf2f(p1.z);
    a3 += bf2f(p0.w) + bf2f(p1.w);
  }
  if (i < E) {
    const int u0 = scols[i];
    const ushort4 p0 = *(const ushort4*)(xqq + (size_t)u0 * 32 + lo);
    a0 += bf2f(p0.x);
    a1 += bf2f(p0.y);
    a2 += bf2f(p0.z);
    a3 += bf2f(p0.w);
  }
  ushort4 o;
  o.x = f2bf(a0); o.y = f2bf(a1); o.z = f2bf(a2); o.w = f2bf(a3);
  *(ushort4*)(aggb + (size_t)v * DD + q * 32 + lo) = o;
}

// K3: fused MLP. 391 blocks x 256 thr, 128 rows/block.
// GEMM1 -> BN1 stats -> spin1 -> BN1+ReLU -> GEMM2 -> BN2 stats -> spin2 ->
// BN2+ReLU -> fp32 out. Capacity-safe spin (see header).
__global__ __launch_bounds__(256, 2) void k_mlp(
    const unsigned short* __restrict__ aggb, float* __restrict__ sum1r,
    float* __restrict__ sumsq1r, const float* __restrict__ g1,
    const float* __restrict__ be1, const unsigned short* __restrict__ W1b,
    const float* __restrict__ b1, const unsigned short* __restrict__ W2b,
    const float* __restrict__ b2, float* __restrict__ sum2r,
    float* __restrict__ sumsq2r, const float* __restrict__ g2,
    const float* __restrict__ be2, float* __restrict__ scale1,
    float* __restrict__ shift1, float* __restrict__ scale2,
    float* __restrict__ shift2, int* __restrict__ syncw,
    float* __restrict__ out) {
  __shared__ unsigned short sT[128 * LDA];  // 34.8KB: agg tile, then h1 tile
  __shared__ float lsc[DD];
  __shared__ float lsh[DD];
  __shared__ int amlast;
  const int tid = threadIdx.x;
  const int bk = blockIdx.x;
  const int wv = tid >> 6;
  const int lane = tid & 63;
  const int quad = lane >> 4;
  const int l16 = lane & 15;
  const int rowq = bk * 128 + wv * 32 + quad * 4;

  // stage agg rows [bk*128, +128) -> sT (clamped; pad rows are copies -> finite)
#pragma unroll
  for (int it = 0; it < 8; ++it) {
    const int idx = it * 256 + tid;
    const int row = idx >> 4, seg = idx & 15;
    int grow = bk * 128 + row;
    grow = grow < NN ? grow : NN - 1;
    *(u16x8*)&sT[row * LDA + seg * 8] =
        *(const u16x8*)(aggb + (size_t)grow * DD + seg * 8);
  }
  __syncthreads();

  // ---- GEMM1: rows wv*32..+32 (m=0,1), cols 0..127 (n=0..7), K=128
  f32x4 acc[2][8];
#pragma unroll
  for (int m = 0; m < 2; ++m)
#pragma unroll
    for (int n = 0; n < 8; ++n) acc[m][n] = (f32x4){0.f, 0.f, 0.f, 0.f};
#pragma unroll
  for (int kk = 0; kk < 4; ++kk) {
    const bf16x8 a0 =
        *(const bf16x8*)&sT[(wv * 32 + l16) * LDA + kk * 32 + quad * 8];
    const bf16x8 a1 =
        *(const bf16x8*)&sT[(wv * 32 + 16 + l16) * LDA + kk * 32 + quad * 8];
#pragma unroll
    for (int n = 0; n < 8; ++n) {
      const bf16x8 bf = *(const bf16x8*)(W1b + (size_t)(n * 16 + l16) * DD +
                                         kk * 32 + quad * 8);
      acc[0][n] = __builtin_amdgcn_mfma_f32_16x16x32_bf16(a0, bf, acc[0][n], 0, 0, 0);
      acc[1][n] = __builtin_amdgcn_mfma_f32_16x16x32_bf16(a1, bf, acc[1][n], 0, 0, 0);
    }
  }
  // bias + BN1 replica stats (guard pad rows)
#pragma unroll
  for (int n = 0; n < 8; ++n) {
    const int col = n * 16 + l16;
    const float bv = b1[col];
    float sv = 0.f, qv = 0.f;
#pragma unroll
    for (int m = 0; m < 2; ++m)
#pragma unroll
      for (int r = 0; r < 4; ++r) {
        const float o = acc[m][n][r] + bv;
        acc[m][n][r] = o;
        if (rowq + m * 16 + r < NN) { sv += o; qv += o * o; }
      }
    sv += __shfl_xor(sv, 16); qv += __shfl_xor(qv, 16);
    sv += __shfl_xor(sv, 32); qv += __shfl_xor(qv, 32);
    if (quad == 0) {
      const int rep = (bk & (NREP - 1)) * DD;
      atomicAdd(&sum1r[rep + col], sv);
      atomicAdd(&sumsq1r[rep + col], qv);
    }
  }
  __syncthreads();  // stats RMWs drained; sT(agg) dead -> becomes h1 tile
  // h1 -> sT (bf16, identical rounding to old h1b path)
#pragma unroll
  for (int m = 0; m < 2; ++m)
#pragma unroll
    for (int n = 0; n < 8; ++n)
#pragma unroll
      for (int r = 0; r < 4; ++r)
        sT[(wv * 32 + m * 16 + quad * 4 + r) * LDA + n * 16 + l16] =
            f2bf(acc[m][n][r]);

  // done1 / winner collapse / flag1 (fence-free: syncthreads drains vmcnt)
  if (tid == 0) amlast = (atomicAdd(&syncw[0], 1) == MLP_B - 1) ? 1 : 0;
  __syncthreads();
  if (amlast) {
    if (tid < DD) {
      float sm = 0.f, qm = 0.f;
#pragma unroll
      for (int r = 0; r < NREP; ++r) {
        sm += ldw(&sum1r[r * DD + tid]);
        qm += ldw(&sumsq1r[r * DD + tid]);
      }
      const float inv_n = 1.0f / (float)NN;
      const float mean = sm * inv_n;
      const float var = qm * inv_n - mean * mean;
      const float sc = g1[tid] * rsqrtf(var + BN_EPS);
      stw(&scale1[tid], sc);
      stw(&shift1[tid], be1[tid] - mean * sc);
    }
    __syncthreads();  // drain scale/shift stores before flag
    if (tid == 0)
      __hip_atomic_store(&syncw[1], 1, __ATOMIC_RELAXED, __HIP_MEMORY_SCOPE_AGENT);
  }
  if (tid == 0) {
    while (__hip_atomic_load(&syncw[1], __ATOMIC_RELAXED,
                             __HIP_MEMORY_SCOPE_AGENT) == 0)
      __builtin_amdgcn_s_sleep(32);
  }
  __syncthreads();
  if (tid < DD) {
    lsc[tid] = ldw(&scale1[tid]);
    lsh[tid] = ldw(&shift1[tid]);
  }
  __syncthreads();

  // ---- GEMM2: A = relu(BN1(h1)) on the fly from sT
  f32x4 acc2[2][8];
#pragma unroll
  for (int m = 0; m < 2; ++m)
#pragma unroll
    for (int n = 0; n < 8; ++n) acc2[m][n] = (f32x4){0.f, 0.f, 0.f, 0.f};
#pragma unroll
  for (int kk = 0; kk < 4; ++kk) {
    const int kb = kk * 32 + quad * 8;
    const float4 s0 = *(const float4*)&lsc[kb];
    const float4 s1 = *(const float4*)&lsc[kb + 4];
    const float4 h0 = *(const float4*)&lsh[kb];
    const float4 h1v = *(const float4*)&lsh[kb + 4];
    const u16x8 x0 = *(const u16x8*)&sT[(wv * 32 + l16) * LDA + kb];
    const u16x8 x1 = *(const u16x8*)&sT[(wv * 32 + 16 + l16) * LDA + kb];
    bf16x8 af0, af1;
    af0[0] = (short)f2bf(fmaxf(fmaf(s0.x, bf2f(x0[0]), h0.x), 0.f));
    af0[1] = (short)f2bf(fmaxf(fmaf(s0.y, bf2f(x0[1]), h0.y), 0.f));
    af0[2] = (short)f2bf(fmaxf(fmaf(s0.z, bf2f(x0[2]), h0.z), 0.f));
    af0[3] = (short)f2bf(fmaxf(fmaf(s0.w, bf2f(x0[3]), h0.w), 0.f));
    af0[4] = (short)f2bf(fmaxf(fmaf(s1.x, bf2f(x0[4]), h1v.x), 0.f));
    af0[5] = (short)f2bf(fmaxf(fmaf(s1.y, bf2f(x0[5]), h1v.y), 0.f));
    af0[6] = (short)f2bf(fmaxf(fmaf(s1.z, bf2f(x0[6]), h1v.z), 0.f));
    af0[7] = (short)f2bf(fmaxf(fmaf(s1.w, bf2f(x0[7]), h1v.w), 0.f));
    af1[0] = (short)f2bf(fmaxf(fmaf(s0.x, bf2f(x1[0]), h0.x), 0.f));
    af1[1] = (short)f2bf(fmaxf(fmaf(s0.y, bf2f(x1[1]), h0.y), 0.f));
    af1[2] = (short)f2bf(fmaxf(fmaf(s0.z, bf2f(x1[2]), h0.z), 0.f));
    af1[3] = (short)f2bf(fmaxf(fmaf(s0.w, bf2f(x1[3]), h0.w), 0.f));
    af1[4] = (short)f2bf(fmaxf(fmaf(s1.x, bf2f(x1[4]), h1v.x), 0.f));
    af1[5] = (short)f2bf(fmaxf(fmaf(s1.y, bf2f(x1[5]), h1v.y), 0.f));
    af1[6] = (short)f2bf(fmaxf(fmaf(s1.z, bf2f(x1[6]), h1v.z), 0.f));
    af1[7] = (short)f2bf(fmaxf(fmaf(s1.w, bf2f(x1[7]), h1v.w), 0.f));
#pragma unroll
    for (int n = 0; n < 8; ++n) {
      const bf16x8 bf =
          *(const bf16x8*)(W2b + (size_t)(n * 16 + l16) * DD + kb);
      acc2[0][n] = __builtin_amdgcn_mfma_f32_16x16x32_bf16(af0, bf, acc2[0][n], 0, 0, 0);
      acc2[1][n] = __builtin_amdgcn_mfma_f32_16x16x32_bf16(af1, bf, acc2[1][n], 0, 0, 0);
    }
  }
  // bias2 + BN2 replica stats
#pragma unroll
  for (int n = 0; n < 8; ++n) {
    const int col = n * 16 + l16;
    const float bv = b2[col];
    float sv = 0.f, qv = 0.f;
#pragma unroll
    for (int m = 0; m < 2; ++m)
#pragma unroll
      for (int r = 0; r < 4; ++r) {
        const float o = acc2[m][n][r] + bv;
        acc2[m][n][r] = o;
        if (rowq + m * 16 + r < NN) { sv += o; qv += o * o; }
      }
    sv += __shfl_xor(sv, 16); qv += __shfl_xor(qv, 16);
    sv += __shfl_xor(sv, 32); qv += __shfl_xor(qv, 32);
    if (quad == 0) {
      const int rep = (bk & (NREP - 1)) * DD;
      atomicAdd(&sum2r[rep + col], sv);
      atomicAdd(&sumsq2r[rep + col], qv);
    }
  }
  __syncthreads();  // stats drained
  if (tid == 0) amlast = (atomicAdd(&syncw[2], 1) == MLP_B - 1) ? 1 : 0;
  __syncthreads();
  if (amlast) {
    if (tid < DD) {
      float sm = 0.f, qm = 0.f;
#pragma unroll
      for (int r = 0; r < NREP; ++r) {
        sm += ldw(&sum2r[r * DD + tid]);
        qm += ldw(&sumsq2r[r * DD + tid]);
      }
      const float inv_n = 1.0f / (float)NN;
      const float mean = sm * inv_n;
      const float var = qm * inv_n - mean * mean;
      const float sc = g2[tid] * rsqrtf(var + BN_EPS);
      stw(&scale2[tid], sc);
      stw(&shift2[tid], be2[tid] - mean * sc);
    }
    __syncthreads();
    if (tid == 0)
      __hip_atomic_store(&syncw[3], 1, __ATOMIC_RELAXED, __HIP_MEMORY_SCOPE_AGENT);
  }
  if (tid == 0) {
    while (__hip_atomic_load(&syncw[3], __ATOMIC_RELAXED,
                             __HIP_MEMORY_SCOPE_AGENT) == 0)
      __builtin_amdgcn_s_sleep(32);
  }
  __syncthreads();
  if (tid < DD) {
    lsc[tid] = ldw(&scale2[tid]);
    lsh[tid] = ldw(&shift2[tid]);
  }
  __syncthreads();
  // BN2 + ReLU applied to fp32 acc -> out (overwrites d_out scratch: safe,
  // every block is past all scratch reads once flag2 is set)
#pragma unroll
  for (int n = 0; n < 8; ++n) {
    const int col = n * 16 + l16;
    const float sc = lsc[col];
    const float sh = lsh[col];
#pragma unroll
    for (int m = 0; m < 2; ++m)
#pragma unroll
      for (int r = 0; r < 4; ++r) {
        const int row = rowq + m * 16 + r;
        if (row < NN)
          out[(size_t)row * DD + col] = fmaxf(fmaf(sc, acc2[m][n][r], sh), 0.f);
      }
  }
}

// ---------------------------------------------------------------------------
extern "C" void kernel_launch(void* const* d_in, const int* in_sizes, int n_in,
                              void* d_out, int out_size, void* d_ws, size_t ws_size,
                              hipStream_t stream) {
  const float* x = (const float*)d_in[0];
  const int* ei = (const int*)d_in[1];
  const float* eps = (const float*)d_in[2];
  const float* W1 = (const float*)d_in[3];
  const float* b1 = (const float*)d_in[4];
  const float* g1 = (const float*)d_in[5];
  const float* be1 = (const float*)d_in[6];
  const float* W2 = (const float*)d_in[7];
  const float* b2 = (const float*)d_in[8];
  const float* g2 = (const float*)d_in[9];
  const float* be2 = (const float*)d_in[10];
  float* out = (float*)d_out;

  const int* rows = ei;
  const int* cols = ei + EE;

  // d_out scratch (all dead before the final out write)
  int* bcur = (int*)d_out;                                  // NBUCK ints
  unsigned short* xq = (unsigned short*)d_out + 2000000;    // byte 4.0M, 12.8MB
  unsigned int* bbuf = (unsigned int*)((char*)d_out + 16800000);  // 6.4MB
  unsigned short* W1b = (unsigned short*)d_out + 11640000;  // byte 23.28M
  unsigned short* W2b = (unsigned short*)d_out + 11680000;  // byte 23.36M
  float* reps = (float*)d_out + 5875000;                    // byte 23.5M, 64KB
  float* sum1r = reps;
  float* sumsq1r = reps + NREP * DD;
  float* sum2r = reps + 2 * NREP * DD;
  float* sumsq2r = reps + 3 * NREP * DD;

  // d_ws: agg | stats/sync tail (never overwritten by out)
  unsigned short* aggb = (unsigned short*)d_ws;             // 12.8MB
  float* stf = (float*)((char*)d_ws + 12800000);
  float* scale1 = stf + 0;
  float* shift1 = stf + 128;
  float* scale2 = stf + 256;
  float* shift2 = stf + 384;
  int* syncw = (int*)(stf + 512);

  // 1. prep: x -> column-blocked bf16 xq, W1b/W2b, zero bcur/reps/syncw
  k_prep<<<XCONV_B + 32, 256, 0, stream>>>(x, W1, W2, xq, W1b, W2b, bcur, reps,
                                           syncw);
  // 2. bin edges into 16-row buckets
  k_bin0<<<BIN_BLOCKS, 256, 0, stream>>>(rows, cols, bcur, bbuf);
  // 3. pass-sliced aggregation (4 L2-resident passes) -> aggb
  k_agg<<<4 * NBUCK, 128, 0, stream>>>(xq, eps, bcur, bbuf, aggb);
  // 4. fused MLP: GEMM1+BN1+ReLU+GEMM2+BN2+ReLU -> fp32 out
  k_mlp<<<MLP_B, 256, 0, stream>>>(aggb, sum1r, sumsq1r, g1, be1, W1b, b1,
                                   W2b, b2, sum2r, sumsq2r, g2, be2, scale1,
                                   shift1, scale2, shift2, syncw, out);
}